// Round 2
// baseline (354.984 us; speedup 1.0000x reference)
//
#include <hip/hip_runtime.h>

#define Tn 1024
#define Hn 16
#define Dn 1024
#define DHn 64
// SCALE * log2(e): Q is pre-scaled by this, softmax then uses exp2 directly.
#define QSCALE 0.18033688011112042f

typedef unsigned short u16;
typedef unsigned long long ull;
typedef __bf16 bf16x8 __attribute__((ext_vector_type(8)));
typedef float f32x4 __attribute__((ext_vector_type(4)));

__device__ __forceinline__ u16 f2bf(float f) {
  union { float f; unsigned u; } v; v.f = f;
  return (u16)((v.u + 0x7FFFu + ((v.u >> 16) & 1u)) >> 16);
}
__device__ __forceinline__ float bf2f(u16 s) {
  union { unsigned u; float f; } v; v.u = ((unsigned)s) << 16;
  return v.f;
}
__device__ __forceinline__ f32x4 mfma16(bf16x8 a, bf16x8 b, f32x4 c) {
  return __builtin_amdgcn_mfma_f32_16x16x32_bf16(a, b, c, 0, 0, 0);
}

// ---------------- convert fp32 -> bf16 (linear) ----------------
__global__ void k_convert(const float* __restrict__ src, u16* __restrict__ dst, int n) {
  int i = (blockIdx.x * blockDim.x + threadIdx.x) * 4;
  if (i >= n) return;
  float4 v = *(const float4*)(src + i);
  union { u16 s[4]; uint2 u; } o;
  o.s[0] = f2bf(v.x); o.s[1] = f2bf(v.y); o.s[2] = f2bf(v.z); o.s[3] = f2bf(v.w);
  *(uint2*)(dst + i) = o.u;
}

// ---------------- pack bool mask bytes -> 64-bit words (bit k = mask[base+k]) ----------------
__global__ __launch_bounds__(256) void k_maskpack(const unsigned char* __restrict__ m,
                                                  unsigned long long* __restrict__ mb) {
  int wi = blockIdx.x * 4 + (threadIdx.x >> 6);
  int lane = threadIdx.x & 63;
  unsigned char v = m[((size_t)wi << 6) + lane];
  unsigned long long bal = __ballot(v != 0);
  if (lane == 0) mb[wi] = bal;
}

// ---------------- transpose + convert: W[K][N] fp32 -> Wt[N][K] bf16 ----------------
__global__ void k_transpose_convert(const float* __restrict__ W, u16* __restrict__ Wt) {
  __shared__ float tile[32][33];
  int n0 = blockIdx.x * 32, k0 = blockIdx.y * 32;
  int tx = threadIdx.x, ty = threadIdx.y; // (32,8)
  #pragma unroll
  for (int i = 0; i < 4; i++)
    tile[ty + 8*i][tx] = W[(size_t)(k0 + ty + 8*i) * Dn + n0 + tx];
  __syncthreads();
  #pragma unroll
  for (int i = 0; i < 4; i++)
    Wt[(size_t)(n0 + ty + 8*i) * Dn + k0 + tx] = f2bf(tile[tx][ty + 8*i]);
}

// ---------------- GEMM: C[M,N] = A[M,K] @ B, given Bt[N,K]; bf16 in/out ----------------
// mode 0: cols 0..1023 -> dst0 scattered [B,H,T,DH] (scaled); cols 1024..2047 -> dst1
//         stored TRANSPOSED as [B,H,DH,T] with packed uint2 stores (4 t-rows/store).
// mode 1: linear write + fp32 bias.
__global__ __launch_bounds__(256) void k_gemm_bt(const u16* __restrict__ A, const u16* __restrict__ Bt,
                                                 u16* __restrict__ dst0, u16* __restrict__ dst1,
                                                 const float* __restrict__ bias, float scale, int mode) {
  __shared__ __align__(16) u16 Al[128][40];
  __shared__ __align__(16) u16 Bl[128][40];
  int m0 = blockIdx.y * 128, n0 = blockIdx.x * 128;
  int tid = threadIdx.x;
  int w = tid >> 6, lane = tid & 63, g = lane >> 4, lr = lane & 15;
  int wr = w >> 1, wc = w & 1;
  f32x4 acc[4][4] = {};
  int sr = tid >> 2, sc = tid & 3;
  const u16* Ap0 = &A[(size_t)(m0 + sr) * Dn + sc * 8];
  const u16* Ap1 = &A[(size_t)(m0 + sr + 64) * Dn + sc * 8];
  const u16* Bp0 = &Bt[(size_t)(n0 + sr) * Dn + sc * 8];
  const u16* Bp1 = &Bt[(size_t)(n0 + sr + 64) * Dn + sc * 8];
  int4 ra0 = *(const int4*)Ap0;
  int4 ra1 = *(const int4*)Ap1;
  int4 rb0 = *(const int4*)Bp0;
  int4 rb1 = *(const int4*)Bp1;
  for (int k0 = 0; k0 < Dn; k0 += 32) {
    __syncthreads();
    *(int4*)&Al[sr][sc*8]      = ra0;
    *(int4*)&Al[sr + 64][sc*8] = ra1;
    *(int4*)&Bl[sr][sc*8]      = rb0;
    *(int4*)&Bl[sr + 64][sc*8] = rb1;
    __syncthreads();
    if (k0 + 32 < Dn) {
      ra0 = *(const int4*)(Ap0 + k0 + 32);
      ra1 = *(const int4*)(Ap1 + k0 + 32);
      rb0 = *(const int4*)(Bp0 + k0 + 32);
      rb1 = *(const int4*)(Bp1 + k0 + 32);
    }
    bf16x8 a[4], b[4];
    #pragma unroll
    for (int mi = 0; mi < 4; mi++) a[mi] = *(const bf16x8*)&Al[wr*64 + mi*16 + lr][g*8];
    #pragma unroll
    for (int ni = 0; ni < 4; ni++) b[ni] = *(const bf16x8*)&Bl[wc*64 + ni*16 + lr][g*8];
    #pragma unroll
    for (int mi = 0; mi < 4; mi++)
      #pragma unroll
      for (int ni = 0; ni < 4; ni++)
        acc[mi][ni] = mfma16(a[mi], b[ni], acc[mi][ni]);
  }
  #pragma unroll
  for (int mi = 0; mi < 4; mi++)
    #pragma unroll
    for (int ni = 0; ni < 4; ni++) {
      int row0 = m0 + wr*64 + mi*16 + g*4;
      int col = n0 + wc*64 + ni*16 + lr;
      if (mode == 0) {
        int bb = row0 >> 10, tt0 = row0 & 1023;
        int hh = col >> 6, dd = col & 63;
        if (hh < 16) {
          u16* p = dst0 + (((size_t)(bb*16 + hh) << 10) + (size_t)tt0) * 64 + dd;
          #pragma unroll
          for (int r = 0; r < 4; r++) p[(size_t)r * 64] = f2bf(acc[mi][ni][r] * scale);
        } else {
          // V^T: [b][head][dd][t], 4 consecutive t per lane -> packed 8B store
          union { u16 s[4]; uint2 u; } o;
          #pragma unroll
          for (int r = 0; r < 4; r++) o.s[r] = f2bf(acc[mi][ni][r]);
          *(uint2*)(dst1 + (((size_t)((bb*16 + (hh - 16)) * 64 + dd)) << 10) + tt0) = o.u;
        }
      } else {
        #pragma unroll
        for (int r = 0; r < 4; r++)
          dst0[(size_t)(row0 + r) * Dn + col] = f2bf(acc[mi][ni][r] + bias[col]);
      }
    }
}

// ---------------- flash attention with Music-Transformer skew ----------------
// grid (T/64, H, B), block 256 = 4 independent waves (NO barriers).
// Wave w owns q-rows q0+16w..+15. K read direct from global [b,h,t,d];
// V read direct from global V^T [b,h,d,t]. Fixed-max softmax (scores bounded),
// row-sum accumulated via ones-MFMA.
__global__ __launch_bounds__(256) void k_attn(const u16* __restrict__ Qb, const u16* __restrict__ Kb,
                                              const u16* __restrict__ VT, const u16* __restrict__ Eb,
                                              const unsigned long long* __restrict__ mbits,
                                              u16* __restrict__ ctx) {
  __shared__ __align__(16) u16 RP[4][16][72]; // per-wave P tile (bf16)
  int h = blockIdx.y, b = blockIdx.z;
  int q0 = blockIdx.x * 64;
  int tid = threadIdx.x;
  int w = tid >> 6, lane = tid & 63, g = lane >> 4, lr = lane & 15;
  int qw0 = q0 + w * 16;
  size_t headoff = (size_t)(b * Hn + h) * Tn * DHn;
  const u16* Kg = Kb + headoff;
  const u16* Vg = VT + headoff;   // [64][1024]
  bf16x8 qf0 = *(const bf16x8*)&Qb[headoff + (size_t)(qw0 + lr)*64 + g*8];
  bf16x8 qf1 = *(const bf16x8*)&Qb[headoff + (size_t)(qw0 + lr)*64 + 32 + g*8];
  f32x4 O[4] = {};
  f32x4 Os = {0.f, 0.f, 0.f, 0.f};
  union { u16 s[8]; bf16x8 v; } one8;
  #pragma unroll
  for (int j = 0; j < 8; j++) one8.s[j] = 0x3F80u; // bf16 1.0

  // loop-invariant skew-shuffle source lanes + register-set predicates:
  // skew(rowq,col) = REL[rowq][col-rowq+15]; producer lane = same g-group,
  // lane (lr-rowq+15)&15, register-set c (if lr<=rowq) else c+1, same reg r.
  int srcl[4]; bool psel[4];
  #pragma unroll
  for (int r = 0; r < 4; r++) {
    int rowq = g*4 + r;
    srcl[r] = (lane & 48) + ((lr - rowq + 15) & 15);
    psel[r] = (lr <= rowq);
  }
  const unsigned long long* mrow = mbits + ((size_t)(b * Tn + qw0 + g*4) << 4);

  #pragma unroll 1
  for (int k0 = 0; k0 < Tn; k0 += 64) {
    // packed mask words: bit (c*16+lr) of mw[r] masks (rowq, k0+c*16+lr)
    uint2 mw[4];
    #pragma unroll
    for (int r = 0; r < 4; r++)
      mw[r] = *(const uint2*)(mrow + (size_t)r * 16 + (k0 >> 6));

    // REL[q][j] = Q[q] . E[rmin + j], j in [0,80)
    int rmin = k0 - qw0 + 1008; // k0 - qw0 - 15 + (Tn-1)
    f32x4 Rm[5];
    #pragma unroll
    for (int jt = 0; jt < 5; jt++) {
      const u16* ep = &Eb[(size_t)(rmin + jt*16 + lr) * 64 + g*8];
      f32x4 R = {0.f, 0.f, 0.f, 0.f};
      R = mfma16(qf0, *(const bf16x8*)ep, R);
      R = mfma16(qf1, *(const bf16x8*)(ep + 32), R);
      Rm[jt] = R;
    }
    // S = Q K^T  (rows q, cols kv) -- K fragments straight from global
    f32x4 S[4];
    #pragma unroll
    for (int c = 0; c < 4; c++) {
      const u16* kp = &Kg[(size_t)(k0 + c*16 + lr) * 64 + g*8];
      f32x4 z = {0.f, 0.f, 0.f, 0.f};
      z = mfma16(qf0, *(const bf16x8*)kp, z);
      z = mfma16(qf1, *(const bf16x8*)(kp + 32), z);
      S[c] = z;
    }
    // V^T fragments (issued early; consumed at PV after softmax)
    bf16x8 vf[8];
    #pragma unroll
    for (int ct = 0; ct < 4; ct++) {
      const u16* vp = &Vg[(size_t)(ct*16 + lr) * 1024 + k0 + g*8];
      vf[ct*2]     = *(const bf16x8*)vp;
      vf[ct*2 + 1] = *(const bf16x8*)(vp + 32);
    }
    // redistribute skew values in-register (ds_bpermute)
    float sh[5][4];
    #pragma unroll
    for (int s5 = 0; s5 < 5; s5++)
      #pragma unroll
      for (int r = 0; r < 4; r++)
        sh[s5][r] = __shfl(Rm[s5][r], srcl[r], 64);

    // combine + mask + exp2 (fixed-max: scores are bounded) + P write
    #pragma unroll
    for (int c = 0; c < 4; c++)
      #pragma unroll
      for (int r = 0; r < 4; r++) {
        float s = S[c][r] + (psel[r] ? sh[c][r] : sh[c+1][r]);
        unsigned bit;
        if (c == 0)      bit = (mw[r].x >> lr) & 1u;
        else if (c == 1) bit = (mw[r].x >> (16 + lr)) & 1u;
        else if (c == 2) bit = (mw[r].y >> lr) & 1u;
        else             bit = (mw[r].y >> (16 + lr)) & 1u;
        s = bit ? -1e9f : s;
        RP[w][g*4 + r][c*16 + lr] = f2bf(__builtin_amdgcn_exp2f(s));
      }
    // PV + row-sum via ones-MFMA (LDS in-order per wave; no barrier needed)
    bf16x8 pa0 = *(const bf16x8*)&RP[w][lr][g*8];
    bf16x8 pa1 = *(const bf16x8*)&RP[w][lr][32 + g*8];
    #pragma unroll
    for (int ct = 0; ct < 4; ct++) {
      O[ct] = mfma16(pa0, vf[ct*2],     O[ct]);
      O[ct] = mfma16(pa1, vf[ct*2 + 1], O[ct]);
    }
    Os = mfma16(pa0, one8.v, Os);
    Os = mfma16(pa1, one8.v, Os);
  }
  float inv[4];
  #pragma unroll
  for (int r = 0; r < 4; r++) inv[r] = 1.f / Os[r];
  #pragma unroll
  for (int ct = 0; ct < 4; ct++)
    #pragma unroll
    for (int r = 0; r < 4; r++) {
      int rowq = g*4 + r, col = ct*16 + lr;
      ctx[(size_t)(b*Tn + qw0 + rowq) * 1024 + h*64 + col] = f2bf(O[ct][r] * inv[r]);
    }
}

// ---------------- residual + LayerNorm ----------------
__global__ __launch_bounds__(256) void k_ln(const float* __restrict__ x, const u16* __restrict__ o,
                                            const float* __restrict__ gamma, const float* __restrict__ beta,
                                            float* __restrict__ out) {
  int m = blockIdx.x, tid = threadIdx.x;
  int w = tid >> 6, lane = tid & 63;
  const float* xr = x + (size_t)m * Dn;
  const u16* orow = o + (size_t)m * Dn;
  float4 xv = *(const float4*)&xr[tid*4];
  union { uint2 u; u16 s[4]; } ou;
  ou.u = *(const uint2*)&orow[tid*4];
  float y[4];
  y[0] = xv.x + bf2f(ou.s[0]);
  y[1] = xv.y + bf2f(ou.s[1]);
  y[2] = xv.z + bf2f(ou.s[2]);
  y[3] = xv.w + bf2f(ou.s[3]);
  float s = y[0]+y[1]+y[2]+y[3];
  float s2 = y[0]*y[0]+y[1]*y[1]+y[2]*y[2]+y[3]*y[3];
  #pragma unroll
  for (int off = 1; off < 64; off <<= 1) { s += __shfl_xor(s, off); s2 += __shfl_xor(s2, off); }
  __shared__ float red[8];
  if (lane == 0) { red[w] = s; red[4 + w] = s2; }
  __syncthreads();
  float Sa = red[0]+red[1]+red[2]+red[3];
  float Sb = red[4]+red[5]+red[6]+red[7];
  float mu = Sa * (1.f/1024.f);
  float var = Sb * (1.f/1024.f) - mu*mu;
  float rstd = rsqrtf(var + 1e-5f);
  #pragma unroll
  for (int i = 0; i < 4; i++) {
    int j = tid*4 + i;
    out[(size_t)m*Dn + j] = (y[i] - mu) * rstd * gamma[j] + beta[j];
  }
}

extern "C" void kernel_launch(void* const* d_in, const int* in_sizes, int n_in,
                              void* d_out, int out_size, void* d_ws, size_t ws_size,
                              hipStream_t stream) {
  const float* x    = (const float*)d_in[0];
  const float* ctxI = (const float*)d_in[1];
  const unsigned char* mask = (const unsigned char*)d_in[2];
  const float* lut  = (const float*)d_in[3];
  const float* Wq   = (const float*)d_in[4];
  const float* Wk   = (const float*)d_in[5];
  const float* Wv   = (const float*)d_in[6];
  const float* Wo   = (const float*)d_in[7];
  const float* bo   = (const float*)d_in[8];
  const float* gamma= (const float*)d_in[9];
  const float* beta = (const float*)d_in[10];
  float* out = (float*)d_out;

  u16* xbf = (u16*)d_ws;
  u16* cbf  = xbf + 4194304;
  u16* WqT  = cbf + 4194304;
  u16* WkT  = WqT + 1048576;
  u16* WvT  = WkT + 1048576;   // contiguous with WkT -> fused KV GEMM reads [2048][1024]
  u16* WoT  = WvT + 1048576;
  u16* Ebf  = WoT + 1048576;
  u16* Qbf  = Ebf + 131072;
  u16* Kbf  = Qbf + 4194304;
  u16* Vbf  = Kbf + 4194304;   // holds V^T [B,H,DH,T]
  u16* ctxb = Vbf + 4194304;
  u16* obf  = ctxb + 4194304;
  unsigned long long* mbits = (unsigned long long*)(obf + 4194304); // 65536 words = 512 KB

  k_maskpack<<<16384, 256, 0, stream>>>(mask, mbits);
  k_convert<<<4096, 256, 0, stream>>>(x, xbf, 4194304);
  k_convert<<<4096, 256, 0, stream>>>(ctxI, cbf, 4194304);
  k_convert<<<128, 256, 0, stream>>>(lut, Ebf, 131008);
  dim3 tb(32, 8), tg(32, 32);
  k_transpose_convert<<<tg, tb, 0, stream>>>(Wq, WqT);
  k_transpose_convert<<<tg, tb, 0, stream>>>(Wk, WkT);
  k_transpose_convert<<<tg, tb, 0, stream>>>(Wv, WvT);
  k_transpose_convert<<<tg, tb, 0, stream>>>(Wo, WoT);
  k_gemm_bt<<<dim3(8, 32),  256, 0, stream>>>(xbf, WqT, Qbf, nullptr, nullptr, QSCALE, 0);
  k_gemm_bt<<<dim3(16, 32), 256, 0, stream>>>(cbf, WkT, Kbf, Vbf,    nullptr, 1.0f,   0);
  k_attn<<<dim3(16, 16, 4), 256, 0, stream>>>(Qbf, Kbf, Vbf, Ebf, mbits, ctxb);
  k_gemm_bt<<<dim3(8, 32),  256, 0, stream>>>(ctxb, WoT, obf, nullptr, bo, 1.0f, 1);
  k_ln<<<4096, 256, 0, stream>>>(x, obf, gamma, beta, out);
}

// Round 3
// 223.907 us; speedup vs baseline: 1.5854x; 1.5854x over previous
//
#include <hip/hip_runtime.h>

#define Tn 1024
#define Hn 16
#define Dn 1024
#define DHn 64
#define KVSPLIT 2
// SCALE * log2(e): Q is pre-scaled by this, softmax then uses exp2 directly.
#define QSCALE 0.18033688011112042f

typedef unsigned short u16;
typedef unsigned long long ull;
typedef __bf16 bf16x8 __attribute__((ext_vector_type(8)));
typedef float f32x4 __attribute__((ext_vector_type(4)));

__device__ __forceinline__ u16 f2bf(float f) {
  union { float f; unsigned u; } v; v.f = f;
  return (u16)((v.u + 0x7FFFu + ((v.u >> 16) & 1u)) >> 16);
}
__device__ __forceinline__ float bf2f(u16 s) {
  union { unsigned u; float f; } v; v.u = ((unsigned)s) << 16;
  return v.f;
}
__device__ __forceinline__ f32x4 mfma16(bf16x8 a, bf16x8 b, f32x4 c) {
  return __builtin_amdgcn_mfma_f32_16x16x32_bf16(a, b, c, 0, 0, 0);
}

// ---------------- convert fp32 -> bf16 (linear) ----------------
__global__ void k_convert(const float* __restrict__ src, u16* __restrict__ dst, int n) {
  int i = (blockIdx.x * blockDim.x + threadIdx.x) * 4;
  if (i >= n) return;
  float4 v = *(const float4*)(src + i);
  union { u16 s[4]; uint2 u; } o;
  o.s[0] = f2bf(v.x); o.s[1] = f2bf(v.y); o.s[2] = f2bf(v.z); o.s[3] = f2bf(v.w);
  *(uint2*)(dst + i) = o.u;
}

// ---------------- pack bool mask bytes -> 64-bit words (bit k = mask[base+k]) ----------------
__global__ __launch_bounds__(256) void k_maskpack(const unsigned char* __restrict__ m,
                                                  unsigned long long* __restrict__ mb) {
  int wi = blockIdx.x * 4 + (threadIdx.x >> 6);
  int lane = threadIdx.x & 63;
  unsigned char v = m[((size_t)wi << 6) + lane];
  unsigned long long bal = __ballot(v != 0);
  if (lane == 0) mb[wi] = bal;
}

// ---------------- transpose + convert: W[K][N] fp32 -> Wt[N][K] bf16 ----------------
__global__ void k_transpose_convert(const float* __restrict__ W, u16* __restrict__ Wt) {
  __shared__ float tile[32][33];
  int n0 = blockIdx.x * 32, k0 = blockIdx.y * 32;
  int tx = threadIdx.x, ty = threadIdx.y; // (32,8)
  #pragma unroll
  for (int i = 0; i < 4; i++)
    tile[ty + 8*i][tx] = W[(size_t)(k0 + ty + 8*i) * Dn + n0 + tx];
  __syncthreads();
  #pragma unroll
  for (int i = 0; i < 4; i++)
    Wt[(size_t)(n0 + ty + 8*i) * Dn + k0 + tx] = f2bf(tile[tx][ty + 8*i]);
}

// ---------------- GEMM: C[M,N] = A[M,K] @ B, given Bt[N,K]; bf16 in/out ----------------
// mode 0: cols 0..1023 -> dst0 scattered [B,H,T,DH] (scaled); cols 1024..2047 -> dst1
//         stored TRANSPOSED as [B,H,DH,T] with packed uint2 stores (4 t-rows/store).
// mode 1: linear write + fp32 bias.
__global__ __launch_bounds__(256) void k_gemm_bt(const u16* __restrict__ A, const u16* __restrict__ Bt,
                                                 u16* __restrict__ dst0, u16* __restrict__ dst1,
                                                 const float* __restrict__ bias, float scale, int mode) {
  __shared__ __align__(16) u16 Al[128][40];
  __shared__ __align__(16) u16 Bl[128][40];
  int m0 = blockIdx.y * 128, n0 = blockIdx.x * 128;
  int tid = threadIdx.x;
  int w = tid >> 6, lane = tid & 63, g = lane >> 4, lr = lane & 15;
  int wr = w >> 1, wc = w & 1;
  f32x4 acc[4][4] = {};
  int sr = tid >> 2, sc = tid & 3;
  const u16* Ap0 = &A[(size_t)(m0 + sr) * Dn + sc * 8];
  const u16* Ap1 = &A[(size_t)(m0 + sr + 64) * Dn + sc * 8];
  const u16* Bp0 = &Bt[(size_t)(n0 + sr) * Dn + sc * 8];
  const u16* Bp1 = &Bt[(size_t)(n0 + sr + 64) * Dn + sc * 8];
  int4 ra0 = *(const int4*)Ap0;
  int4 ra1 = *(const int4*)Ap1;
  int4 rb0 = *(const int4*)Bp0;
  int4 rb1 = *(const int4*)Bp1;
  for (int k0 = 0; k0 < Dn; k0 += 32) {
    __syncthreads();
    *(int4*)&Al[sr][sc*8]      = ra0;
    *(int4*)&Al[sr + 64][sc*8] = ra1;
    *(int4*)&Bl[sr][sc*8]      = rb0;
    *(int4*)&Bl[sr + 64][sc*8] = rb1;
    __syncthreads();
    if (k0 + 32 < Dn) {
      ra0 = *(const int4*)(Ap0 + k0 + 32);
      ra1 = *(const int4*)(Ap1 + k0 + 32);
      rb0 = *(const int4*)(Bp0 + k0 + 32);
      rb1 = *(const int4*)(Bp1 + k0 + 32);
    }
    bf16x8 a[4], b[4];
    #pragma unroll
    for (int mi = 0; mi < 4; mi++) a[mi] = *(const bf16x8*)&Al[wr*64 + mi*16 + lr][g*8];
    #pragma unroll
    for (int ni = 0; ni < 4; ni++) b[ni] = *(const bf16x8*)&Bl[wc*64 + ni*16 + lr][g*8];
    #pragma unroll
    for (int mi = 0; mi < 4; mi++)
      #pragma unroll
      for (int ni = 0; ni < 4; ni++)
        acc[mi][ni] = mfma16(a[mi], b[ni], acc[mi][ni]);
  }
  #pragma unroll
  for (int mi = 0; mi < 4; mi++)
    #pragma unroll
    for (int ni = 0; ni < 4; ni++) {
      int row0 = m0 + wr*64 + mi*16 + g*4;
      int col = n0 + wc*64 + ni*16 + lr;
      if (mode == 0) {
        int bb = row0 >> 10, tt0 = row0 & 1023;
        int hh = col >> 6, dd = col & 63;
        if (hh < 16) {
          u16* p = dst0 + (((size_t)(bb*16 + hh) << 10) + (size_t)tt0) * 64 + dd;
          #pragma unroll
          for (int r = 0; r < 4; r++) p[(size_t)r * 64] = f2bf(acc[mi][ni][r] * scale);
        } else {
          // V^T: [b][head][dd][t], 4 consecutive t per lane -> packed 8B store
          union { u16 s[4]; uint2 u; } o;
          #pragma unroll
          for (int r = 0; r < 4; r++) o.s[r] = f2bf(acc[mi][ni][r]);
          *(uint2*)(dst1 + (((size_t)((bb*16 + (hh - 16)) * 64 + dd)) << 10) + tt0) = o.u;
        }
      } else {
        #pragma unroll
        for (int r = 0; r < 4; r++)
          dst0[(size_t)(row0 + r) * Dn + col] = f2bf(acc[mi][ni][r] + bias[col]);
      }
    }
}

// ---------------- flash attention with Music-Transformer skew ----------------
// grid (T/64, H, KVSPLIT*B), block 256. Wave w owns q-rows q0+16w..+15.
// LDS-staged K tile and V^T tile (vectorized, no transpose work in-kernel).
// Fixed-max softmax (scores bounded -> no running max), row-sum via ones-MFMA.
// Each z-block handles kv range [s*T/KVSPLIT, (s+1)*T/KVSPLIT); partials are
// directly additive (no max renormalization) -> combine kernel sums them.
__global__ __launch_bounds__(256) void k_attn(const u16* __restrict__ Qb, const u16* __restrict__ Kb,
                                              const u16* __restrict__ VT, const u16* __restrict__ Eb,
                                              const unsigned long long* __restrict__ mbits,
                                              u16* __restrict__ Opart, float* __restrict__ Lpart) {
  __shared__ __align__(16) u16 Kl[64][72];
  __shared__ __align__(16) u16 Vt[64][72];   // V^T tile: Vt[d][kv-local]
  __shared__ __align__(16) u16 RP[4][16][72]; // per-wave P tile (bf16)
  int h = blockIdx.y;
  int zi = blockIdx.z;            // s*B + b
  int b = zi & 3;
  int kv0 = (zi >> 2) * (Tn / KVSPLIT);
  int kv_end = kv0 + Tn / KVSPLIT;
  int q0 = blockIdx.x * 64;
  int tid = threadIdx.x;
  int w = tid >> 6, lane = tid & 63, g = lane >> 4, lr = lane & 15;
  int qw0 = q0 + w * 16;
  size_t headoff = (size_t)(b * Hn + h) * Tn * DHn;
  bf16x8 qf0 = *(const bf16x8*)&Qb[headoff + (size_t)(qw0 + lr)*64 + g*8];
  bf16x8 qf1 = *(const bf16x8*)&Qb[headoff + (size_t)(qw0 + lr)*64 + 32 + g*8];
  f32x4 O[4] = {};
  f32x4 Os = {0.f, 0.f, 0.f, 0.f};
  union { u16 s[8]; bf16x8 v; } one8;
  #pragma unroll
  for (int j = 0; j < 8; j++) one8.s[j] = 0x3F80u; // bf16 1.0

  // loop-invariant skew-shuffle source lanes + register-set predicates:
  // skew(rowq,col) = REL[rowq][col-rowq+15]; producer lane = same g-group,
  // lane (lr-rowq+15)&15, register-set c (if lr<=rowq) else c+1, same reg r.
  int srcl[4]; bool psel[4];
  #pragma unroll
  for (int r = 0; r < 4; r++) {
    int rowq = g*4 + r;
    srcl[r] = (lane & 48) + ((lr - rowq + 15) & 15);
    psel[r] = (lr <= rowq);
  }
  const unsigned long long* mrow = mbits + ((size_t)(b * Tn + qw0 + g*4) << 4);

  // staging: thread handles rows (tid>>3) and (tid>>3)+32, col chunk (tid&7)*8
  int srow = tid >> 3, sc8 = tid & 7;
  const u16* Kgs = Kb + headoff + (size_t)srow * 64 + sc8 * 8;  // K[b,h,t,d]
  const u16* Vgs = VT + headoff + (size_t)srow * 1024 + sc8 * 8; // V^T[b,h,d,t]
  int4 kA = *(const int4*)(Kgs + (size_t)kv0 * 64);
  int4 kB = *(const int4*)(Kgs + (size_t)(kv0 + 32) * 64);
  int4 vA = *(const int4*)(Vgs + kv0);
  int4 vB = *(const int4*)(Vgs + 32 * 1024 + kv0);

  for (int k0 = kv0; k0 < kv_end; k0 += 64) {
    __syncthreads();
    *(int4*)&Kl[srow][sc8*8]      = kA;
    *(int4*)&Kl[srow + 32][sc8*8] = kB;
    *(int4*)&Vt[srow][sc8*8]      = vA;
    *(int4*)&Vt[srow + 32][sc8*8] = vB;
    __syncthreads();
    if (k0 + 64 < kv_end) {   // T14: prefetch next tile under this tile's compute
      kA = *(const int4*)(Kgs + (size_t)(k0 + 64) * 64);
      kB = *(const int4*)(Kgs + (size_t)(k0 + 96) * 64);
      vA = *(const int4*)(Vgs + k0 + 64);
      vB = *(const int4*)(Vgs + 32 * 1024 + k0 + 64);
    }
    // packed mask words: bit (c*16+lr) of mw[r] masks (rowq, k0+c*16+lr)
    uint2 mw[4];
    #pragma unroll
    for (int r = 0; r < 4; r++)
      mw[r] = *(const uint2*)(mrow + (size_t)r * 16 + (k0 >> 6));

    // REL[q][j] = Q[q] . E[rmin + j], j in [0,80)
    int rmin = k0 - qw0 + 1008; // k0 - qw0 - 15 + (Tn-1)
    f32x4 Rm[5];
    #pragma unroll
    for (int jt = 0; jt < 5; jt++) {
      const u16* ep = &Eb[(size_t)(rmin + jt*16 + lr) * 64 + g*8];
      f32x4 R = {0.f, 0.f, 0.f, 0.f};
      R = mfma16(qf0, *(const bf16x8*)ep, R);
      R = mfma16(qf1, *(const bf16x8*)(ep + 32), R);
      Rm[jt] = R;
    }
    // S = Q K^T  (rows q, cols kv)
    f32x4 S[4];
    #pragma unroll
    for (int c = 0; c < 4; c++) {
      f32x4 z = {0.f, 0.f, 0.f, 0.f};
      bf16x8 kf0 = *(const bf16x8*)&Kl[c*16 + lr][g*8];
      bf16x8 kf1 = *(const bf16x8*)&Kl[c*16 + lr][32 + g*8];
      z = mfma16(qf0, kf0, z);
      z = mfma16(qf1, kf1, z);
      S[c] = z;
    }
    // redistribute skew values in-register (ds_bpermute)
    float sh[5][4];
    #pragma unroll
    for (int s5 = 0; s5 < 5; s5++)
      #pragma unroll
      for (int r = 0; r < 4; r++)
        sh[s5][r] = __shfl(Rm[s5][r], srcl[r], 64);

    // combine + mask + exp2 (fixed-max: scores bounded) + P write
    #pragma unroll
    for (int c = 0; c < 4; c++)
      #pragma unroll
      for (int r = 0; r < 4; r++) {
        float s = S[c][r] + (psel[r] ? sh[c][r] : sh[c+1][r]);
        unsigned bit;
        if (c == 0)      bit = (mw[r].x >> lr) & 1u;
        else if (c == 1) bit = (mw[r].x >> (16 + lr)) & 1u;
        else if (c == 2) bit = (mw[r].y >> lr) & 1u;
        else             bit = (mw[r].y >> (16 + lr)) & 1u;
        s = bit ? -1e9f : s;
        RP[w][g*4 + r][c*16 + lr] = f2bf(__builtin_amdgcn_exp2f(s));
      }
    // PV + row-sum via ones-MFMA (LDS in-order within the wave; no barrier needed)
    bf16x8 pa0 = *(const bf16x8*)&RP[w][lr][g*8];
    bf16x8 pa1 = *(const bf16x8*)&RP[w][lr][32 + g*8];
    #pragma unroll
    for (int ct = 0; ct < 4; ct++) {
      bf16x8 vf0 = *(const bf16x8*)&Vt[ct*16 + lr][g*8];
      bf16x8 vf1 = *(const bf16x8*)&Vt[ct*16 + lr][32 + g*8];
      O[ct] = mfma16(pa0, vf0, O[ct]);
      O[ct] = mfma16(pa1, vf1, O[ct]);
    }
    Os = mfma16(pa0, one8.v, Os);
    Os = mfma16(pa1, one8.v, Os);
  }
  // store unnormalized partial O (bf16) and row-sums l (f32)
  #pragma unroll
  for (int ct = 0; ct < 4; ct++)
    #pragma unroll
    for (int r = 0; r < 4; r++) {
      int rowq = g*4 + r, col = ct*16 + lr;
      Opart[((size_t)zi * Tn + qw0 + rowq) * 1024 + h*64 + col] = f2bf(O[ct][r]);
    }
  if (lr == 0) {
    #pragma unroll
    for (int r = 0; r < 4; r++)
      Lpart[((size_t)zi * Hn + h) * Tn + qw0 + g*4 + r] = Os[r];
  }
}

// ---------------- combine KV-split partials: ctx = (sum O_s) / (sum l_s) ----------------
__global__ __launch_bounds__(256) void k_combine(const u16* __restrict__ Op, const float* __restrict__ Lp,
                                                 u16* __restrict__ ctx) {
  int m = blockIdx.x;            // b*T + t
  int b = m >> 10, t = m & 1023;
  int tid = threadIdx.x;
  int j0 = tid * 4, h = j0 >> 6;
  float l = Lp[((size_t)b * Hn + h) * Tn + t] +
            Lp[((size_t)(4 + b) * Hn + h) * Tn + t];
  float invl = 1.f / l;
  union { uint2 u; u16 s[4]; } a, c;
  a.u = *(const uint2*)&Op[((size_t)b * Tn + t) * 1024 + j0];
  c.u = *(const uint2*)&Op[((size_t)(4 + b) * Tn + t) * 1024 + j0];
  union { u16 s[4]; uint2 u; } o;
  #pragma unroll
  for (int i = 0; i < 4; i++)
    o.s[i] = f2bf((bf2f(a.s[i]) + bf2f(c.s[i])) * invl);
  *(uint2*)&ctx[((size_t)b * Tn + t) * 1024 + j0] = o.u;
}

// ---------------- residual + LayerNorm ----------------
__global__ __launch_bounds__(256) void k_ln(const float* __restrict__ x, const u16* __restrict__ o,
                                            const float* __restrict__ gamma, const float* __restrict__ beta,
                                            float* __restrict__ out) {
  int m = blockIdx.x, tid = threadIdx.x;
  int w = tid >> 6, lane = tid & 63;
  const float* xr = x + (size_t)m * Dn;
  const u16* orow = o + (size_t)m * Dn;
  float4 xv = *(const float4*)&xr[tid*4];
  union { uint2 u; u16 s[4]; } ou;
  ou.u = *(const uint2*)&orow[tid*4];
  float y[4];
  y[0] = xv.x + bf2f(ou.s[0]);
  y[1] = xv.y + bf2f(ou.s[1]);
  y[2] = xv.z + bf2f(ou.s[2]);
  y[3] = xv.w + bf2f(ou.s[3]);
  float s = y[0]+y[1]+y[2]+y[3];
  float s2 = y[0]*y[0]+y[1]*y[1]+y[2]*y[2]+y[3]*y[3];
  #pragma unroll
  for (int off = 1; off < 64; off <<= 1) { s += __shfl_xor(s, off); s2 += __shfl_xor(s2, off); }
  __shared__ float red[8];
  if (lane == 0) { red[w] = s; red[4 + w] = s2; }
  __syncthreads();
  float Sa = red[0]+red[1]+red[2]+red[3];
  float Sb = red[4]+red[5]+red[6]+red[7];
  float mu = Sa * (1.f/1024.f);
  float var = Sb * (1.f/1024.f) - mu*mu;
  float rstd = rsqrtf(var + 1e-5f);
  #pragma unroll
  for (int i = 0; i < 4; i++) {
    int j = tid*4 + i;
    out[(size_t)m*Dn + j] = (y[i] - mu) * rstd * gamma[j] + beta[j];
  }
}

extern "C" void kernel_launch(void* const* d_in, const int* in_sizes, int n_in,
                              void* d_out, int out_size, void* d_ws, size_t ws_size,
                              hipStream_t stream) {
  const float* x    = (const float*)d_in[0];
  const float* ctxI = (const float*)d_in[1];
  const unsigned char* mask = (const unsigned char*)d_in[2];
  const float* lut  = (const float*)d_in[3];
  const float* Wq   = (const float*)d_in[4];
  const float* Wk   = (const float*)d_in[5];
  const float* Wv   = (const float*)d_in[6];
  const float* Wo   = (const float*)d_in[7];
  const float* bo   = (const float*)d_in[8];
  const float* gamma= (const float*)d_in[9];
  const float* beta = (const float*)d_in[10];
  float* out = (float*)d_out;

  u16* xbf = (u16*)d_ws;
  u16* cbf  = xbf + 4194304;
  u16* WqT  = cbf + 4194304;
  u16* WkT  = WqT + 1048576;
  u16* WvT  = WkT + 1048576;   // contiguous with WkT -> fused KV GEMM reads [2048][1024]
  u16* WoT  = WvT + 1048576;
  u16* Ebf  = WoT + 1048576;
  u16* Qbf  = Ebf + 131072;
  u16* Kbf  = Qbf + 4194304;
  u16* Vbf  = Kbf + 4194304;   // holds V^T [B,H,DH,T]
  u16* ctxb = Vbf + 4194304;
  u16* obf  = ctxb + 4194304;
  unsigned long long* mbits = (unsigned long long*)(obf + 4194304); // 65536 words = 512 KB

  // KV-split partial buffers alias DEAD regions during attn:
  //   Opart (16.8 MB, bf16, [2*B][T][H*DH]) over xbf+cbf (consumed by the Q/KV GEMMs).
  //   Lpart (512 KB, f32, [2*B][H][T]) over obf (first written by the O-GEMM, later).
  u16* Opart = xbf;
  float* Lpart = (float*)obf;

  k_maskpack<<<16384, 256, 0, stream>>>(mask, mbits);
  k_convert<<<4096, 256, 0, stream>>>(x, xbf, 4194304);
  k_convert<<<4096, 256, 0, stream>>>(ctxI, cbf, 4194304);
  k_convert<<<128, 256, 0, stream>>>(lut, Ebf, 131008);
  dim3 tb(32, 8), tg(32, 32);
  k_transpose_convert<<<tg, tb, 0, stream>>>(Wq, WqT);
  k_transpose_convert<<<tg, tb, 0, stream>>>(Wk, WkT);
  k_transpose_convert<<<tg, tb, 0, stream>>>(Wv, WvT);
  k_transpose_convert<<<tg, tb, 0, stream>>>(Wo, WoT);
  k_gemm_bt<<<dim3(8, 32),  256, 0, stream>>>(xbf, WqT, Qbf, nullptr, nullptr, QSCALE, 0);
  k_gemm_bt<<<dim3(16, 32), 256, 0, stream>>>(cbf, WkT, Kbf, Vbf,    nullptr, 1.0f,   0);
  k_attn<<<dim3(16, 16, 8), 256, 0, stream>>>(Qbf, Kbf, Vbf, Ebf, mbits, Opart, Lpart);
  k_combine<<<4096, 256, 0, stream>>>(Opart, Lpart, ctxb);
  k_gemm_bt<<<dim3(8, 32),  256, 0, stream>>>(ctxb, WoT, obf, nullptr, bo, 1.0f, 1);
  k_ln<<<4096, 256, 0, stream>>>(x, obf, gamma, beta, out);
}

// Round 4
// 218.430 us; speedup vs baseline: 1.6252x; 1.0251x over previous
//
#include <hip/hip_runtime.h>

#define Tn 1024
#define Hn 16
#define Dn 1024
#define DHn 64
#define KVSPLIT 2
// SCALE * log2(e): Q is pre-scaled by this, softmax then uses exp2 directly.
#define QSCALE 0.18033688011112042f

typedef unsigned short u16;
typedef unsigned long long ull;
typedef __bf16 bf16x8 __attribute__((ext_vector_type(8)));
typedef float f32x4 __attribute__((ext_vector_type(4)));

__device__ __forceinline__ u16 f2bf(float f) {
  union { float f; unsigned u; } v; v.f = f;
  return (u16)((v.u + 0x7FFFu + ((v.u >> 16) & 1u)) >> 16);
}
__device__ __forceinline__ float bf2f(u16 s) {
  union { unsigned u; float f; } v; v.u = ((unsigned)s) << 16;
  return v.f;
}
__device__ __forceinline__ f32x4 mfma16(bf16x8 a, bf16x8 b, f32x4 c) {
  return __builtin_amdgcn_mfma_f32_16x16x32_bf16(a, b, c, 0, 0, 0);
}

// ---------------- convert fp32 -> bf16 (linear) ----------------
__global__ void k_convert(const float* __restrict__ src, u16* __restrict__ dst, int n) {
  int i = (blockIdx.x * blockDim.x + threadIdx.x) * 4;
  if (i >= n) return;
  float4 v = *(const float4*)(src + i);
  union { u16 s[4]; uint2 u; } o;
  o.s[0] = f2bf(v.x); o.s[1] = f2bf(v.y); o.s[2] = f2bf(v.z); o.s[3] = f2bf(v.w);
  *(uint2*)(dst + i) = o.u;
}

// ---------------- pack bool mask bytes -> 64-bit words (bit k = mask[base+k]) ----------------
__global__ __launch_bounds__(256) void k_maskpack(const unsigned char* __restrict__ m,
                                                  unsigned long long* __restrict__ mb) {
  int wi = blockIdx.x * 4 + (threadIdx.x >> 6);
  int lane = threadIdx.x & 63;
  unsigned char v = m[((size_t)wi << 6) + lane];
  unsigned long long bal = __ballot(v != 0);
  if (lane == 0) mb[wi] = bal;
}

// ---------------- transpose + convert: W[K][N] fp32 -> Wt[N][K] bf16 ----------------
__global__ void k_transpose_convert(const float* __restrict__ W, u16* __restrict__ Wt) {
  __shared__ float tile[32][33];
  int n0 = blockIdx.x * 32, k0 = blockIdx.y * 32;
  int tx = threadIdx.x, ty = threadIdx.y; // (32,8)
  #pragma unroll
  for (int i = 0; i < 4; i++)
    tile[ty + 8*i][tx] = W[(size_t)(k0 + ty + 8*i) * Dn + n0 + tx];
  __syncthreads();
  #pragma unroll
  for (int i = 0; i < 4; i++)
    Wt[(size_t)(n0 + ty + 8*i) * Dn + k0 + tx] = f2bf(tile[tx][ty + 8*i]);
}

// ---------------- GEMM: C[M,N] = A[M,K] @ B, given Bt[N,K]; bf16 in/out ----------------
// mode 0: cols 0..1023 -> dst0 scattered [B,H,T,DH] (scaled); cols 1024..2047 -> dst1
//         stored TRANSPOSED as [B,H,DH,T] with packed uint2 stores (4 t-rows/store).
// mode 1: linear write + fp32 bias.
__global__ __launch_bounds__(256) void k_gemm_bt(const u16* __restrict__ A, const u16* __restrict__ Bt,
                                                 u16* __restrict__ dst0, u16* __restrict__ dst1,
                                                 const float* __restrict__ bias, float scale, int mode) {
  __shared__ __align__(16) u16 Al[128][40];
  __shared__ __align__(16) u16 Bl[128][40];
  int m0 = blockIdx.y * 128, n0 = blockIdx.x * 128;
  int tid = threadIdx.x;
  int w = tid >> 6, lane = tid & 63, g = lane >> 4, lr = lane & 15;
  int wr = w >> 1, wc = w & 1;
  f32x4 acc[4][4] = {};
  int sr = tid >> 2, sc = tid & 3;
  const u16* Ap0 = &A[(size_t)(m0 + sr) * Dn + sc * 8];
  const u16* Ap1 = &A[(size_t)(m0 + sr + 64) * Dn + sc * 8];
  const u16* Bp0 = &Bt[(size_t)(n0 + sr) * Dn + sc * 8];
  const u16* Bp1 = &Bt[(size_t)(n0 + sr + 64) * Dn + sc * 8];
  int4 ra0 = *(const int4*)Ap0;
  int4 ra1 = *(const int4*)Ap1;
  int4 rb0 = *(const int4*)Bp0;
  int4 rb1 = *(const int4*)Bp1;
  for (int k0 = 0; k0 < Dn; k0 += 32) {
    __syncthreads();
    *(int4*)&Al[sr][sc*8]      = ra0;
    *(int4*)&Al[sr + 64][sc*8] = ra1;
    *(int4*)&Bl[sr][sc*8]      = rb0;
    *(int4*)&Bl[sr + 64][sc*8] = rb1;
    __syncthreads();
    if (k0 + 32 < Dn) {
      ra0 = *(const int4*)(Ap0 + k0 + 32);
      ra1 = *(const int4*)(Ap1 + k0 + 32);
      rb0 = *(const int4*)(Bp0 + k0 + 32);
      rb1 = *(const int4*)(Bp1 + k0 + 32);
    }
    bf16x8 a[4], b[4];
    #pragma unroll
    for (int mi = 0; mi < 4; mi++) a[mi] = *(const bf16x8*)&Al[wr*64 + mi*16 + lr][g*8];
    #pragma unroll
    for (int ni = 0; ni < 4; ni++) b[ni] = *(const bf16x8*)&Bl[wc*64 + ni*16 + lr][g*8];
    #pragma unroll
    for (int mi = 0; mi < 4; mi++)
      #pragma unroll
      for (int ni = 0; ni < 4; ni++)
        acc[mi][ni] = mfma16(a[mi], b[ni], acc[mi][ni]);
  }
  #pragma unroll
  for (int mi = 0; mi < 4; mi++)
    #pragma unroll
    for (int ni = 0; ni < 4; ni++) {
      int row0 = m0 + wr*64 + mi*16 + g*4;
      int col = n0 + wc*64 + ni*16 + lr;
      if (mode == 0) {
        int bb = row0 >> 10, tt0 = row0 & 1023;
        int hh = col >> 6, dd = col & 63;
        if (hh < 16) {
          u16* p = dst0 + (((size_t)(bb*16 + hh) << 10) + (size_t)tt0) * 64 + dd;
          #pragma unroll
          for (int r = 0; r < 4; r++) p[(size_t)r * 64] = f2bf(acc[mi][ni][r] * scale);
        } else {
          // V^T: [b][head][dd][t], 4 consecutive t per lane -> packed 8B store
          union { u16 s[4]; uint2 u; } o;
          #pragma unroll
          for (int r = 0; r < 4; r++) o.s[r] = f2bf(acc[mi][ni][r]);
          *(uint2*)(dst1 + (((size_t)((bb*16 + (hh - 16)) * 64 + dd)) << 10) + tt0) = o.u;
        }
      } else {
        #pragma unroll
        for (int r = 0; r < 4; r++)
          dst0[(size_t)(row0 + r) * Dn + col] = f2bf(acc[mi][ni][r] + bias[col]);
      }
    }
}

// ---------------- flash attention with Music-Transformer skew ----------------
// grid (KVSPLIT*B, H, T/128), block 512 = 8 waves sharing one K/V staging.
// blockIdx.x = zi (split*B + b) is the FASTEST dim so the 8 q-blocks sharing a
// K/V chunk differ only in the slowest dim -> same XCD -> L2 reuse.
// Wave w owns q-rows q0+16w..+15. Fixed-max softmax, row-sum via ones-MFMA.
__global__ __launch_bounds__(512) void k_attn(const u16* __restrict__ Qb, const u16* __restrict__ Kb,
                                              const u16* __restrict__ VT, const u16* __restrict__ Eb,
                                              const unsigned long long* __restrict__ mbits,
                                              u16* __restrict__ Opart, float* __restrict__ Lpart) {
  __shared__ __align__(16) u16 Kl[64][72];
  __shared__ __align__(16) u16 Vt[64][72];   // V^T tile: Vt[d][kv-local]
  __shared__ __align__(16) u16 RP[8][16][72]; // per-wave P tile (bf16)
  int h = blockIdx.y;
  int zi = blockIdx.x;            // s*B + b
  int b = zi & 3;
  int kv0 = (zi >> 2) * (Tn / KVSPLIT);
  int kv_end = kv0 + Tn / KVSPLIT;
  int q0 = blockIdx.z * 128;
  int tid = threadIdx.x;
  int w = tid >> 6, lane = tid & 63, g = lane >> 4, lr = lane & 15;
  int qw0 = q0 + w * 16;
  size_t headoff = (size_t)(b * Hn + h) * Tn * DHn;
  bf16x8 qf0 = *(const bf16x8*)&Qb[headoff + (size_t)(qw0 + lr)*64 + g*8];
  bf16x8 qf1 = *(const bf16x8*)&Qb[headoff + (size_t)(qw0 + lr)*64 + 32 + g*8];
  f32x4 O[4] = {};
  f32x4 Os = {0.f, 0.f, 0.f, 0.f};
  union { u16 s[8]; bf16x8 v; } one8;
  #pragma unroll
  for (int j = 0; j < 8; j++) one8.s[j] = 0x3F80u; // bf16 1.0

  // loop-invariant skew-shuffle source lanes + register-set predicates:
  // skew(rowq,col) = REL[rowq][col-rowq+15]; producer lane = same g-group,
  // lane (lr-rowq+15)&15, register-set c (if lr<=rowq) else c+1, same reg r.
  int srcl[4]; bool psel[4];
  #pragma unroll
  for (int r = 0; r < 4; r++) {
    int rowq = g*4 + r;
    srcl[r] = (lane & 48) + ((lr - rowq + 15) & 15);
    psel[r] = (lr <= rowq);
  }
  const unsigned long long* mrow = mbits + ((size_t)(b * Tn + qw0 + g*4) << 4);

  // staging: 512 threads cover the 64x64 tile once: row tid>>3, col chunk (tid&7)*8
  int srow = tid >> 3, sc8 = tid & 7;
  const u16* Kgs = Kb + headoff + (size_t)srow * 64 + sc8 * 8;  // K[b,h,t,d]
  const u16* Vgs = VT + headoff + (size_t)srow * 1024 + sc8 * 8; // V^T[b,h,d,t]
  int4 kA = *(const int4*)(Kgs + (size_t)kv0 * 64);
  int4 vA = *(const int4*)(Vgs + kv0);

  for (int k0 = kv0; k0 < kv_end; k0 += 64) {
    __syncthreads();
    *(int4*)&Kl[srow][sc8*8] = kA;
    *(int4*)&Vt[srow][sc8*8] = vA;
    __syncthreads();
    if (k0 + 64 < kv_end) {   // T14: prefetch next tile under this tile's compute
      kA = *(const int4*)(Kgs + (size_t)(k0 + 64) * 64);
      vA = *(const int4*)(Vgs + k0 + 64);
    }
    // packed mask words: bit (c*16+lr) of mw[r] masks (rowq, k0+c*16+lr)
    uint2 mw[4];
    #pragma unroll
    for (int r = 0; r < 4; r++)
      mw[r] = *(const uint2*)(mrow + (size_t)r * 16 + (k0 >> 6));

    // REL[q][j] = Q[q] . E[rmin + j], j in [0,80)
    int rmin = k0 - qw0 + 1008; // k0 - qw0 - 15 + (Tn-1)
    f32x4 Rm[5];
    __builtin_amdgcn_s_setprio(1);
    #pragma unroll
    for (int jt = 0; jt < 5; jt++) {
      const u16* ep = &Eb[(size_t)(rmin + jt*16 + lr) * 64 + g*8];
      f32x4 R = {0.f, 0.f, 0.f, 0.f};
      R = mfma16(qf0, *(const bf16x8*)ep, R);
      R = mfma16(qf1, *(const bf16x8*)(ep + 32), R);
      Rm[jt] = R;
    }
    // S = Q K^T  (rows q, cols kv)
    f32x4 S[4];
    #pragma unroll
    for (int c = 0; c < 4; c++) {
      f32x4 z = {0.f, 0.f, 0.f, 0.f};
      bf16x8 kf0 = *(const bf16x8*)&Kl[c*16 + lr][g*8];
      bf16x8 kf1 = *(const bf16x8*)&Kl[c*16 + lr][32 + g*8];
      z = mfma16(qf0, kf0, z);
      z = mfma16(qf1, kf1, z);
      S[c] = z;
    }
    __builtin_amdgcn_s_setprio(0);
    // redistribute skew values in-register (ds_bpermute)
    float sh[5][4];
    #pragma unroll
    for (int s5 = 0; s5 < 5; s5++)
      #pragma unroll
      for (int r = 0; r < 4; r++)
        sh[s5][r] = __shfl(Rm[s5][r], srcl[r], 64);

    // combine + mask + exp2 (fixed-max: scores bounded) + P write
    #pragma unroll
    for (int c = 0; c < 4; c++)
      #pragma unroll
      for (int r = 0; r < 4; r++) {
        float s = S[c][r] + (psel[r] ? sh[c][r] : sh[c+1][r]);
        unsigned bit;
        if (c == 0)      bit = (mw[r].x >> lr) & 1u;
        else if (c == 1) bit = (mw[r].x >> (16 + lr)) & 1u;
        else if (c == 2) bit = (mw[r].y >> lr) & 1u;
        else             bit = (mw[r].y >> (16 + lr)) & 1u;
        s = bit ? -1e9f : s;
        RP[w][g*4 + r][c*16 + lr] = f2bf(__builtin_amdgcn_exp2f(s));
      }
    // PV + row-sum via ones-MFMA (LDS in-order within the wave; no barrier needed)
    bf16x8 pa0 = *(const bf16x8*)&RP[w][lr][g*8];
    bf16x8 pa1 = *(const bf16x8*)&RP[w][lr][32 + g*8];
    __builtin_amdgcn_s_setprio(1);
    #pragma unroll
    for (int ct = 0; ct < 4; ct++) {
      bf16x8 vf0 = *(const bf16x8*)&Vt[ct*16 + lr][g*8];
      bf16x8 vf1 = *(const bf16x8*)&Vt[ct*16 + lr][32 + g*8];
      O[ct] = mfma16(pa0, vf0, O[ct]);
      O[ct] = mfma16(pa1, vf1, O[ct]);
    }
    Os = mfma16(pa0, one8.v, Os);
    Os = mfma16(pa1, one8.v, Os);
    __builtin_amdgcn_s_setprio(0);
  }
  // store unnormalized partial O (bf16) and row-sums l (f32)
  #pragma unroll
  for (int ct = 0; ct < 4; ct++)
    #pragma unroll
    for (int r = 0; r < 4; r++) {
      int rowq = g*4 + r, col = ct*16 + lr;
      Opart[((size_t)zi * Tn + qw0 + rowq) * 1024 + h*64 + col] = f2bf(O[ct][r]);
    }
  if (lr == 0) {
    #pragma unroll
    for (int r = 0; r < 4; r++)
      Lpart[((size_t)zi * Hn + h) * Tn + qw0 + g*4 + r] = Os[r];
  }
}

// ---------------- combine KV-split partials: ctx = (sum O_s) / (sum l_s) ----------------
__global__ __launch_bounds__(256) void k_combine(const u16* __restrict__ Op, const float* __restrict__ Lp,
                                                 u16* __restrict__ ctx) {
  int m = blockIdx.x;            // b*T + t
  int b = m >> 10, t = m & 1023;
  int tid = threadIdx.x;
  int j0 = tid * 4, h = j0 >> 6;
  float l = Lp[((size_t)b * Hn + h) * Tn + t] +
            Lp[((size_t)(4 + b) * Hn + h) * Tn + t];
  float invl = 1.f / l;
  union { uint2 u; u16 s[4]; } a, c;
  a.u = *(const uint2*)&Op[((size_t)b * Tn + t) * 1024 + j0];
  c.u = *(const uint2*)&Op[((size_t)(4 + b) * Tn + t) * 1024 + j0];
  union { u16 s[4]; uint2 u; } o;
  #pragma unroll
  for (int i = 0; i < 4; i++)
    o.s[i] = f2bf((bf2f(a.s[i]) + bf2f(c.s[i])) * invl);
  *(uint2*)&ctx[((size_t)b * Tn + t) * 1024 + j0] = o.u;
}

// ---------------- residual + LayerNorm ----------------
__global__ __launch_bounds__(256) void k_ln(const float* __restrict__ x, const u16* __restrict__ o,
                                            const float* __restrict__ gamma, const float* __restrict__ beta,
                                            float* __restrict__ out) {
  int m = blockIdx.x, tid = threadIdx.x;
  int w = tid >> 6, lane = tid & 63;
  const float* xr = x + (size_t)m * Dn;
  const u16* orow = o + (size_t)m * Dn;
  float4 xv = *(const float4*)&xr[tid*4];
  union { uint2 u; u16 s[4]; } ou;
  ou.u = *(const uint2*)&orow[tid*4];
  float y[4];
  y[0] = xv.x + bf2f(ou.s[0]);
  y[1] = xv.y + bf2f(ou.s[1]);
  y[2] = xv.z + bf2f(ou.s[2]);
  y[3] = xv.w + bf2f(ou.s[3]);
  float s = y[0]+y[1]+y[2]+y[3];
  float s2 = y[0]*y[0]+y[1]*y[1]+y[2]*y[2]+y[3]*y[3];
  #pragma unroll
  for (int off = 1; off < 64; off <<= 1) { s += __shfl_xor(s, off); s2 += __shfl_xor(s2, off); }
  __shared__ float red[8];
  if (lane == 0) { red[w] = s; red[4 + w] = s2; }
  __syncthreads();
  float Sa = red[0]+red[1]+red[2]+red[3];
  float Sb = red[4]+red[5]+red[6]+red[7];
  float mu = Sa * (1.f/1024.f);
  float var = Sb * (1.f/1024.f) - mu*mu;
  float rstd = rsqrtf(var + 1e-5f);
  #pragma unroll
  for (int i = 0; i < 4; i++) {
    int j = tid*4 + i;
    out[(size_t)m*Dn + j] = (y[i] - mu) * rstd * gamma[j] + beta[j];
  }
}

extern "C" void kernel_launch(void* const* d_in, const int* in_sizes, int n_in,
                              void* d_out, int out_size, void* d_ws, size_t ws_size,
                              hipStream_t stream) {
  const float* x    = (const float*)d_in[0];
  const float* ctxI = (const float*)d_in[1];
  const unsigned char* mask = (const unsigned char*)d_in[2];
  const float* lut  = (const float*)d_in[3];
  const float* Wq   = (const float*)d_in[4];
  const float* Wk   = (const float*)d_in[5];
  const float* Wv   = (const float*)d_in[6];
  const float* Wo   = (const float*)d_in[7];
  const float* bo   = (const float*)d_in[8];
  const float* gamma= (const float*)d_in[9];
  const float* beta = (const float*)d_in[10];
  float* out = (float*)d_out;

  u16* xbf = (u16*)d_ws;
  u16* cbf  = xbf + 4194304;
  u16* WqT  = cbf + 4194304;
  u16* WkT  = WqT + 1048576;
  u16* WvT  = WkT + 1048576;   // contiguous with WkT -> fused KV GEMM reads [2048][1024]
  u16* WoT  = WvT + 1048576;
  u16* Ebf  = WoT + 1048576;
  u16* Qbf  = Ebf + 131072;
  u16* Kbf  = Qbf + 4194304;
  u16* Vbf  = Kbf + 4194304;   // holds V^T [B,H,DH,T]
  u16* ctxb = Vbf + 4194304;
  u16* obf  = ctxb + 4194304;
  unsigned long long* mbits = (unsigned long long*)(obf + 4194304); // 65536 words = 512 KB

  // KV-split partial buffers alias DEAD regions during attn:
  //   Opart (16.8 MB, bf16, [2*B][T][H*DH]) over xbf+cbf (consumed by the Q/KV GEMMs).
  //   Lpart (512 KB, f32, [2*B][H][T]) over obf (first written by the O-GEMM, later).
  u16* Opart = xbf;
  float* Lpart = (float*)obf;

  k_maskpack<<<16384, 256, 0, stream>>>(mask, mbits);
  k_convert<<<4096, 256, 0, stream>>>(x, xbf, 4194304);
  k_convert<<<4096, 256, 0, stream>>>(ctxI, cbf, 4194304);
  k_convert<<<128, 256, 0, stream>>>(lut, Ebf, 131008);
  dim3 tb(32, 8), tg(32, 32);
  k_transpose_convert<<<tg, tb, 0, stream>>>(Wq, WqT);
  k_transpose_convert<<<tg, tb, 0, stream>>>(Wk, WkT);
  k_transpose_convert<<<tg, tb, 0, stream>>>(Wv, WvT);
  k_transpose_convert<<<tg, tb, 0, stream>>>(Wo, WoT);
  k_gemm_bt<<<dim3(8, 32),  256, 0, stream>>>(xbf, WqT, Qbf, nullptr, nullptr, QSCALE, 0);
  k_gemm_bt<<<dim3(16, 32), 256, 0, stream>>>(cbf, WkT, Kbf, Vbf,    nullptr, 1.0f,   0);
  k_attn<<<dim3(8, 16, 8), 512, 0, stream>>>(Qbf, Kbf, Vbf, Ebf, mbits, Opart, Lpart);
  k_combine<<<4096, 256, 0, stream>>>(Opart, Lpart, ctxb);
  k_gemm_bt<<<dim3(8, 32),  256, 0, stream>>>(ctxb, WoT, obf, nullptr, bo, 1.0f, 1);
  k_ln<<<4096, 256, 0, stream>>>(x, obf, gamma, beta, out);
}

// Round 5
// 215.550 us; speedup vs baseline: 1.6469x; 1.0134x over previous
//
#include <hip/hip_runtime.h>

#define Tn 1024
#define Hn 16
#define Dn 1024
#define DHn 64
#define KVSPLIT 2
// SCALE * log2(e): Q is pre-scaled by this, softmax then uses exp2 directly.
#define QSCALE 0.18033688011112042f

typedef unsigned short u16;
typedef unsigned long long ull;
typedef __bf16 bf16x8 __attribute__((ext_vector_type(8)));
typedef float f32x4 __attribute__((ext_vector_type(4)));

__device__ __forceinline__ u16 f2bf(float f) {
  union { float f; unsigned u; } v; v.f = f;
  return (u16)((v.u + 0x7FFFu + ((v.u >> 16) & 1u)) >> 16);
}
__device__ __forceinline__ float bf2f(u16 s) {
  union { unsigned u; float f; } v; v.u = ((unsigned)s) << 16;
  return v.f;
}
__device__ __forceinline__ f32x4 mfma16(bf16x8 a, bf16x8 b, f32x4 c) {
  return __builtin_amdgcn_mfma_f32_16x16x32_bf16(a, b, c, 0, 0, 0);
}

// ---------------- convert fp32 -> bf16 (linear) ----------------
__global__ void k_convert(const float* __restrict__ src, u16* __restrict__ dst, int n) {
  int i = (blockIdx.x * blockDim.x + threadIdx.x) * 4;
  if (i >= n) return;
  float4 v = *(const float4*)(src + i);
  union { u16 s[4]; uint2 u; } o;
  o.s[0] = f2bf(v.x); o.s[1] = f2bf(v.y); o.s[2] = f2bf(v.z); o.s[3] = f2bf(v.w);
  *(uint2*)(dst + i) = o.u;
}

// ---------------- pack bool mask bytes -> 64-bit words (bit k = mask[base+k]) ----------------
__global__ __launch_bounds__(256) void k_maskpack(const unsigned char* __restrict__ m,
                                                  unsigned long long* __restrict__ mb) {
  int wi = blockIdx.x * 4 + (threadIdx.x >> 6);
  int lane = threadIdx.x & 63;
  unsigned char v = m[((size_t)wi << 6) + lane];
  unsigned long long bal = __ballot(v != 0);
  if (lane == 0) mb[wi] = bal;
}

// ---------------- transpose + convert: W[K][N] fp32 -> Wt[N][K] bf16 ----------------
__global__ void k_transpose_convert(const float* __restrict__ W, u16* __restrict__ Wt) {
  __shared__ float tile[32][33];
  int n0 = blockIdx.x * 32, k0 = blockIdx.y * 32;
  int tx = threadIdx.x, ty = threadIdx.y; // (32,8)
  #pragma unroll
  for (int i = 0; i < 4; i++)
    tile[ty + 8*i][tx] = W[(size_t)(k0 + ty + 8*i) * Dn + n0 + tx];
  __syncthreads();
  #pragma unroll
  for (int i = 0; i < 4; i++)
    Wt[(size_t)(n0 + ty + 8*i) * Dn + k0 + tx] = f2bf(tile[tx][ty + 8*i]);
}

// ---------------- GEMM: C[M,N] = A[M,K] @ B, given Bt[N,K]; bf16 in/out ----------------
// mode 0: cols 0..1023 -> dst0 scattered [B,H,T,DH] (scaled); cols 1024..2047 -> dst1
//         stored TRANSPOSED as [B,H,DH,T] with packed uint2 stores (4 t-rows/store).
// mode 1: linear write + fp32 bias.
__global__ __launch_bounds__(256) void k_gemm_bt(const u16* __restrict__ A, const u16* __restrict__ Bt,
                                                 u16* __restrict__ dst0, u16* __restrict__ dst1,
                                                 const float* __restrict__ bias, float scale, int mode) {
  __shared__ __align__(16) u16 Al[128][40];
  __shared__ __align__(16) u16 Bl[128][40];
  int m0 = blockIdx.y * 128, n0 = blockIdx.x * 128;
  int tid = threadIdx.x;
  int w = tid >> 6, lane = tid & 63, g = lane >> 4, lr = lane & 15;
  int wr = w >> 1, wc = w & 1;
  f32x4 acc[4][4] = {};
  int sr = tid >> 2, sc = tid & 3;
  const u16* Ap0 = &A[(size_t)(m0 + sr) * Dn + sc * 8];
  const u16* Ap1 = &A[(size_t)(m0 + sr + 64) * Dn + sc * 8];
  const u16* Bp0 = &Bt[(size_t)(n0 + sr) * Dn + sc * 8];
  const u16* Bp1 = &Bt[(size_t)(n0 + sr + 64) * Dn + sc * 8];
  int4 ra0 = *(const int4*)Ap0;
  int4 ra1 = *(const int4*)Ap1;
  int4 rb0 = *(const int4*)Bp0;
  int4 rb1 = *(const int4*)Bp1;
  for (int k0 = 0; k0 < Dn; k0 += 32) {
    __syncthreads();
    *(int4*)&Al[sr][sc*8]      = ra0;
    *(int4*)&Al[sr + 64][sc*8] = ra1;
    *(int4*)&Bl[sr][sc*8]      = rb0;
    *(int4*)&Bl[sr + 64][sc*8] = rb1;
    __syncthreads();
    if (k0 + 32 < Dn) {
      ra0 = *(const int4*)(Ap0 + k0 + 32);
      ra1 = *(const int4*)(Ap1 + k0 + 32);
      rb0 = *(const int4*)(Bp0 + k0 + 32);
      rb1 = *(const int4*)(Bp1 + k0 + 32);
    }
    bf16x8 a[4], b[4];
    #pragma unroll
    for (int mi = 0; mi < 4; mi++) a[mi] = *(const bf16x8*)&Al[wr*64 + mi*16 + lr][g*8];
    #pragma unroll
    for (int ni = 0; ni < 4; ni++) b[ni] = *(const bf16x8*)&Bl[wc*64 + ni*16 + lr][g*8];
    #pragma unroll
    for (int mi = 0; mi < 4; mi++)
      #pragma unroll
      for (int ni = 0; ni < 4; ni++)
        acc[mi][ni] = mfma16(a[mi], b[ni], acc[mi][ni]);
  }
  #pragma unroll
  for (int mi = 0; mi < 4; mi++)
    #pragma unroll
    for (int ni = 0; ni < 4; ni++) {
      int row0 = m0 + wr*64 + mi*16 + g*4;
      int col = n0 + wc*64 + ni*16 + lr;
      if (mode == 0) {
        int bb = row0 >> 10, tt0 = row0 & 1023;
        int hh = col >> 6, dd = col & 63;
        if (hh < 16) {
          u16* p = dst0 + (((size_t)(bb*16 + hh) << 10) + (size_t)tt0) * 64 + dd;
          #pragma unroll
          for (int r = 0; r < 4; r++) p[(size_t)r * 64] = f2bf(acc[mi][ni][r] * scale);
        } else {
          // V^T: [b][head][dd][t], 4 consecutive t per lane -> packed 8B store
          union { u16 s[4]; uint2 u; } o;
          #pragma unroll
          for (int r = 0; r < 4; r++) o.s[r] = f2bf(acc[mi][ni][r]);
          *(uint2*)(dst1 + (((size_t)((bb*16 + (hh - 16)) * 64 + dd)) << 10) + tt0) = o.u;
        }
      } else {
        #pragma unroll
        for (int r = 0; r < 4; r++)
          dst0[(size_t)(row0 + r) * Dn + col] = f2bf(acc[mi][ni][r] + bias[col]);
      }
    }
}

// ---------------- flash attention with Music-Transformer skew ----------------
// grid (KVSPLIT*B, H, T/128), block 512 = 8 waves sharing one K/V staging.
// Each barrier-iter processes TWO 64-kv tiles (128 kv): two independent
// MFMA/softmax/PV chains per phase -> 2x ILP hides pipe latency; barrier
// events per kv halved. Fixed-max softmax, row-sum via ones-MFMA.
__global__ __launch_bounds__(512, 4) void k_attn(const u16* __restrict__ Qb, const u16* __restrict__ Kb,
                                              const u16* __restrict__ VT, const u16* __restrict__ Eb,
                                              const unsigned long long* __restrict__ mbits,
                                              u16* __restrict__ Opart, float* __restrict__ Lpart) {
  __shared__ __align__(16) u16 Kl[128][72];
  __shared__ __align__(16) u16 Vt[64][136];   // V^T tile: Vt[d][kv-local 0..127]
  __shared__ __align__(16) u16 RP[2][8][16][72]; // per-tile, per-wave P (bf16)
  int h = blockIdx.y;
  int zi = blockIdx.x;            // s*B + b
  int b = zi & 3;
  int kv0 = (zi >> 2) * (Tn / KVSPLIT);
  int kv_end = kv0 + Tn / KVSPLIT;
  int q0 = blockIdx.z * 128;
  int tid = threadIdx.x;
  int w = tid >> 6, lane = tid & 63, g = lane >> 4, lr = lane & 15;
  int qw0 = q0 + w * 16;
  size_t headoff = (size_t)(b * Hn + h) * Tn * DHn;
  bf16x8 qf0 = *(const bf16x8*)&Qb[headoff + (size_t)(qw0 + lr)*64 + g*8];
  bf16x8 qf1 = *(const bf16x8*)&Qb[headoff + (size_t)(qw0 + lr)*64 + 32 + g*8];
  f32x4 O[4] = {};
  f32x4 Os = {0.f, 0.f, 0.f, 0.f};
  union { u16 s[8]; bf16x8 v; } one8;
  #pragma unroll
  for (int j = 0; j < 8; j++) one8.s[j] = 0x3F80u; // bf16 1.0

  // loop-invariant skew-shuffle source lanes + register-set predicates:
  // skew(rowq,col) = REL[rowq][col-rowq+15]; producer lane = same g-group,
  // lane (lr-rowq+15)&15, register-set c (if lr<=rowq) else c+1, same reg r.
  int srcl[4]; bool psel[4];
  #pragma unroll
  for (int r = 0; r < 4; r++) {
    int rowq = g*4 + r;
    srcl[r] = (lane & 48) + ((lr - rowq + 15) & 15);
    psel[r] = (lr <= rowq);
  }
  const unsigned long long* mrow = mbits + ((size_t)(b * Tn + qw0 + g*4) << 4);

  // staging (512 threads, 128-kv iter):
  //   K: 128 rows x 64 cols -> rows tid>>3 and +64, chunk (tid&7)*8
  //   V^T: 64 rows x 128 cols -> rows tid>>4 and +32, chunk (tid&15)*8
  int sKr = tid >> 3, sKc = (tid & 7) * 8;
  int sVr = tid >> 4, sVc = (tid & 15) * 8;
  const u16* Kgs = Kb + headoff + (size_t)sKr * 64 + sKc;
  const u16* Vgs = VT + headoff + (size_t)sVr * 1024 + sVc;
  int4 kA = *(const int4*)(Kgs + (size_t)kv0 * 64);
  int4 kB = *(const int4*)(Kgs + (size_t)(kv0 + 64) * 64);
  int4 vA = *(const int4*)(Vgs + kv0);
  int4 vB = *(const int4*)(Vgs + 32 * 1024 + kv0);

  for (int k0 = kv0; k0 < kv_end; k0 += 128) {
    __syncthreads();
    *(int4*)&Kl[sKr][sKc]      = kA;
    *(int4*)&Kl[sKr + 64][sKc] = kB;
    *(int4*)&Vt[sVr][sVc]      = vA;
    *(int4*)&Vt[sVr + 32][sVc] = vB;
    __syncthreads();
    if (k0 + 128 < kv_end) {   // prefetch next 128-kv iter under this compute
      kA = *(const int4*)(Kgs + (size_t)(k0 + 128) * 64);
      kB = *(const int4*)(Kgs + (size_t)(k0 + 192) * 64);
      vA = *(const int4*)(Vgs + k0 + 128);
      vB = *(const int4*)(Vgs + 32 * 1024 + k0 + 128);
    }
    // packed mask words for both tiles
    uint2 mw[2][4];
    #pragma unroll
    for (int t = 0; t < 2; t++)
      #pragma unroll
      for (int r = 0; r < 4; r++)
        mw[t][r] = *(const uint2*)(mrow + (size_t)r * 16 + (k0 >> 6) + t);

    bf16x8 pa[2][2];
    #pragma unroll
    for (int t = 0; t < 2; t++) {
      int kt = k0 + t * 64;
      // REL[q][j] = Q[q] . E[rmin + j], j in [0,80)
      int rmin = kt - qw0 + 1008;
      f32x4 Rm[5];
      __builtin_amdgcn_s_setprio(1);
      #pragma unroll
      for (int jt = 0; jt < 5; jt++) {
        const u16* ep = &Eb[(size_t)(rmin + jt*16 + lr) * 64 + g*8];
        f32x4 R = {0.f, 0.f, 0.f, 0.f};
        R = mfma16(qf0, *(const bf16x8*)ep, R);
        R = mfma16(qf1, *(const bf16x8*)(ep + 32), R);
        Rm[jt] = R;
      }
      // S = Q K^T  (rows q, cols kv)
      f32x4 S[4];
      #pragma unroll
      for (int c = 0; c < 4; c++) {
        f32x4 z = {0.f, 0.f, 0.f, 0.f};
        bf16x8 kf0 = *(const bf16x8*)&Kl[t*64 + c*16 + lr][g*8];
        bf16x8 kf1 = *(const bf16x8*)&Kl[t*64 + c*16 + lr][32 + g*8];
        z = mfma16(qf0, kf0, z);
        z = mfma16(qf1, kf1, z);
        S[c] = z;
      }
      __builtin_amdgcn_s_setprio(0);
      // redistribute skew values in-register (ds_bpermute)
      float sh[5][4];
      #pragma unroll
      for (int s5 = 0; s5 < 5; s5++)
        #pragma unroll
        for (int r = 0; r < 4; r++)
          sh[s5][r] = __shfl(Rm[s5][r], srcl[r], 64);
      // combine + mask + exp2 (fixed-max: scores bounded) + P write
      #pragma unroll
      for (int c = 0; c < 4; c++)
        #pragma unroll
        for (int r = 0; r < 4; r++) {
          float s = S[c][r] + (psel[r] ? sh[c][r] : sh[c+1][r]);
          unsigned bit;
          if (c == 0)      bit = (mw[t][r].x >> lr) & 1u;
          else if (c == 1) bit = (mw[t][r].x >> (16 + lr)) & 1u;
          else if (c == 2) bit = (mw[t][r].y >> lr) & 1u;
          else             bit = (mw[t][r].y >> (16 + lr)) & 1u;
          s = bit ? -1e9f : s;
          RP[t][w][g*4 + r][c*16 + lr] = f2bf(__builtin_amdgcn_exp2f(s));
        }
      pa[t][0] = *(const bf16x8*)&RP[t][w][lr][g*8];
      pa[t][1] = *(const bf16x8*)&RP[t][w][lr][32 + g*8];
    }
    // PV + row-sum via ones-MFMA, both tiles (one big MFMA cluster)
    __builtin_amdgcn_s_setprio(1);
    #pragma unroll
    for (int t = 0; t < 2; t++) {
      #pragma unroll
      for (int ct = 0; ct < 4; ct++) {
        bf16x8 vf0 = *(const bf16x8*)&Vt[ct*16 + lr][t*64 + g*8];
        bf16x8 vf1 = *(const bf16x8*)&Vt[ct*16 + lr][t*64 + 32 + g*8];
        O[ct] = mfma16(pa[t][0], vf0, O[ct]);
        O[ct] = mfma16(pa[t][1], vf1, O[ct]);
      }
      Os = mfma16(pa[t][0], one8.v, Os);
      Os = mfma16(pa[t][1], one8.v, Os);
    }
    __builtin_amdgcn_s_setprio(0);
  }
  // store unnormalized partial O (bf16) and row-sums l (f32)
  #pragma unroll
  for (int ct = 0; ct < 4; ct++)
    #pragma unroll
    for (int r = 0; r < 4; r++) {
      int rowq = g*4 + r, col = ct*16 + lr;
      Opart[((size_t)zi * Tn + qw0 + rowq) * 1024 + h*64 + col] = f2bf(O[ct][r]);
    }
  if (lr == 0) {
    #pragma unroll
    for (int r = 0; r < 4; r++)
      Lpart[((size_t)zi * Hn + h) * Tn + qw0 + g*4 + r] = Os[r];
  }
}

// ---------------- combine KV-split partials: ctx = (sum O_s) / (sum l_s) ----------------
__global__ __launch_bounds__(256) void k_combine(const u16* __restrict__ Op, const float* __restrict__ Lp,
                                                 u16* __restrict__ ctx) {
  int m = blockIdx.x;            // b*T + t
  int b = m >> 10, t = m & 1023;
  int tid = threadIdx.x;
  int j0 = tid * 4, h = j0 >> 6;
  float l = Lp[((size_t)b * Hn + h) * Tn + t] +
            Lp[((size_t)(4 + b) * Hn + h) * Tn + t];
  float invl = 1.f / l;
  union { uint2 u; u16 s[4]; } a, c;
  a.u = *(const uint2*)&Op[((size_t)b * Tn + t) * 1024 + j0];
  c.u = *(const uint2*)&Op[((size_t)(4 + b) * Tn + t) * 1024 + j0];
  union { u16 s[4]; uint2 u; } o;
  #pragma unroll
  for (int i = 0; i < 4; i++)
    o.s[i] = f2bf((bf2f(a.s[i]) + bf2f(c.s[i])) * invl);
  *(uint2*)&ctx[((size_t)b * Tn + t) * 1024 + j0] = o.u;
}

// ---------------- residual + LayerNorm ----------------
__global__ __launch_bounds__(256) void k_ln(const float* __restrict__ x, const u16* __restrict__ o,
                                            const float* __restrict__ gamma, const float* __restrict__ beta,
                                            float* __restrict__ out) {
  int m = blockIdx.x, tid = threadIdx.x;
  int w = tid >> 6, lane = tid & 63;
  const float* xr = x + (size_t)m * Dn;
  const u16* orow = o + (size_t)m * Dn;
  float4 xv = *(const float4*)&xr[tid*4];
  union { uint2 u; u16 s[4]; } ou;
  ou.u = *(const uint2*)&orow[tid*4];
  float y[4];
  y[0] = xv.x + bf2f(ou.s[0]);
  y[1] = xv.y + bf2f(ou.s[1]);
  y[2] = xv.z + bf2f(ou.s[2]);
  y[3] = xv.w + bf2f(ou.s[3]);
  float s = y[0]+y[1]+y[2]+y[3];
  float s2 = y[0]*y[0]+y[1]*y[1]+y[2]*y[2]+y[3]*y[3];
  #pragma unroll
  for (int off = 1; off < 64; off <<= 1) { s += __shfl_xor(s, off); s2 += __shfl_xor(s2, off); }
  __shared__ float red[8];
  if (lane == 0) { red[w] = s; red[4 + w] = s2; }
  __syncthreads();
  float Sa = red[0]+red[1]+red[2]+red[3];
  float Sb = red[4]+red[5]+red[6]+red[7];
  float mu = Sa * (1.f/1024.f);
  float var = Sb * (1.f/1024.f) - mu*mu;
  float rstd = rsqrtf(var + 1e-5f);
  #pragma unroll
  for (int i = 0; i < 4; i++) {
    int j = tid*4 + i;
    out[(size_t)m*Dn + j] = (y[i] - mu) * rstd * gamma[j] + beta[j];
  }
}

extern "C" void kernel_launch(void* const* d_in, const int* in_sizes, int n_in,
                              void* d_out, int out_size, void* d_ws, size_t ws_size,
                              hipStream_t stream) {
  const float* x    = (const float*)d_in[0];
  const float* ctxI = (const float*)d_in[1];
  const unsigned char* mask = (const unsigned char*)d_in[2];
  const float* lut  = (const float*)d_in[3];
  const float* Wq   = (const float*)d_in[4];
  const float* Wk   = (const float*)d_in[5];
  const float* Wv   = (const float*)d_in[6];
  const float* Wo   = (const float*)d_in[7];
  const float* bo   = (const float*)d_in[8];
  const float* gamma= (const float*)d_in[9];
  const float* beta = (const float*)d_in[10];
  float* out = (float*)d_out;

  u16* xbf = (u16*)d_ws;
  u16* cbf  = xbf + 4194304;
  u16* WqT  = cbf + 4194304;
  u16* WkT  = WqT + 1048576;
  u16* WvT  = WkT + 1048576;   // contiguous with WkT -> fused KV GEMM reads [2048][1024]
  u16* WoT  = WvT + 1048576;
  u16* Ebf  = WoT + 1048576;
  u16* Qbf  = Ebf + 131072;
  u16* Kbf  = Qbf + 4194304;
  u16* Vbf  = Kbf + 4194304;   // holds V^T [B,H,DH,T]
  u16* ctxb = Vbf + 4194304;
  u16* obf  = ctxb + 4194304;
  unsigned long long* mbits = (unsigned long long*)(obf + 4194304); // 65536 words = 512 KB

  // KV-split partial buffers alias DEAD regions during attn:
  //   Opart (16.8 MB, bf16, [2*B][T][H*DH]) over xbf+cbf (consumed by the Q/KV GEMMs).
  //   Lpart (512 KB, f32, [2*B][H][T]) over obf (first written by the O-GEMM, later).
  u16* Opart = xbf;
  float* Lpart = (float*)obf;

  k_maskpack<<<16384, 256, 0, stream>>>(mask, mbits);
  k_convert<<<4096, 256, 0, stream>>>(x, xbf, 4194304);
  k_convert<<<4096, 256, 0, stream>>>(ctxI, cbf, 4194304);
  k_convert<<<128, 256, 0, stream>>>(lut, Ebf, 131008);
  dim3 tb(32, 8), tg(32, 32);
  k_transpose_convert<<<tg, tb, 0, stream>>>(Wq, WqT);
  k_transpose_convert<<<tg, tb, 0, stream>>>(Wk, WkT);
  k_transpose_convert<<<tg, tb, 0, stream>>>(Wv, WvT);
  k_transpose_convert<<<tg, tb, 0, stream>>>(Wo, WoT);
  k_gemm_bt<<<dim3(8, 32),  256, 0, stream>>>(xbf, WqT, Qbf, nullptr, nullptr, QSCALE, 0);
  k_gemm_bt<<<dim3(16, 32), 256, 0, stream>>>(cbf, WkT, Kbf, Vbf,    nullptr, 1.0f,   0);
  k_attn<<<dim3(8, 16, 8), 512, 0, stream>>>(Qbf, Kbf, Vbf, Ebf, mbits, Opart, Lpart);
  k_combine<<<4096, 256, 0, stream>>>(Opart, Lpart, ctxb);
  k_gemm_bt<<<dim3(8, 32),  256, 0, stream>>>(ctxb, WoT, obf, nullptr, bo, 1.0f, 1);
  k_ln<<<4096, 256, 0, stream>>>(x, obf, gamma, beta, out);
}

// Round 6
// 209.128 us; speedup vs baseline: 1.6974x; 1.0307x over previous
//
#include <hip/hip_runtime.h>

#define Tn 1024
#define Hn 16
#define Dn 1024
#define DHn 64
#define KVSPLIT 2
// SCALE * log2(e): Q is pre-scaled by this, softmax then uses exp2 directly.
#define QSCALE 0.18033688011112042f

typedef unsigned short u16;
typedef unsigned long long ull;
typedef __bf16 bf16x8 __attribute__((ext_vector_type(8)));
typedef float f32x4 __attribute__((ext_vector_type(4)));

__device__ __forceinline__ u16 f2bf(float f) {
  union { float f; unsigned u; } v; v.f = f;
  return (u16)((v.u + 0x7FFFu + ((v.u >> 16) & 1u)) >> 16);
}
__device__ __forceinline__ float bf2f(u16 s) {
  union { unsigned u; float f; } v; v.u = ((unsigned)s) << 16;
  return v.f;
}
__device__ __forceinline__ f32x4 mfma16(bf16x8 a, bf16x8 b, f32x4 c) {
  return __builtin_amdgcn_mfma_f32_16x16x32_bf16(a, b, c, 0, 0, 0);
}

// ---------------- convert fp32 -> bf16 (linear) ----------------
__global__ void k_convert(const float* __restrict__ src, u16* __restrict__ dst, int n) {
  int i = (blockIdx.x * blockDim.x + threadIdx.x) * 4;
  if (i >= n) return;
  float4 v = *(const float4*)(src + i);
  union { u16 s[4]; uint2 u; } o;
  o.s[0] = f2bf(v.x); o.s[1] = f2bf(v.y); o.s[2] = f2bf(v.z); o.s[3] = f2bf(v.w);
  *(uint2*)(dst + i) = o.u;
}

// ---------------- pack bool mask bytes -> 64-bit words (bit k = mask[base+k]) ----------------
__global__ __launch_bounds__(256) void k_maskpack(const unsigned char* __restrict__ m,
                                                  unsigned long long* __restrict__ mb) {
  int wi = blockIdx.x * 4 + (threadIdx.x >> 6);
  int lane = threadIdx.x & 63;
  unsigned char v = m[((size_t)wi << 6) + lane];
  unsigned long long bal = __ballot(v != 0);
  if (lane == 0) mb[wi] = bal;
}

// ---------------- transpose + convert: W[K][N] fp32 -> Wt[N][K] bf16 ----------------
__global__ void k_transpose_convert(const float* __restrict__ W, u16* __restrict__ Wt) {
  __shared__ float tile[32][33];
  int n0 = blockIdx.x * 32, k0 = blockIdx.y * 32;
  int tx = threadIdx.x, ty = threadIdx.y; // (32,8)
  #pragma unroll
  for (int i = 0; i < 4; i++)
    tile[ty + 8*i][tx] = W[(size_t)(k0 + ty + 8*i) * Dn + n0 + tx];
  __syncthreads();
  #pragma unroll
  for (int i = 0; i < 4; i++)
    Wt[(size_t)(n0 + ty + 8*i) * Dn + k0 + tx] = f2bf(tile[tx][ty + 8*i]);
}

// ---------------- GEMM: C[M,N] = A[M,K] @ B, given Bt[N,K]; bf16 in/out ----------------
// mode 0: cols 0..1023 -> dst0 scattered [B,H,T,DH] (scaled); cols 1024..2047 -> dst1
//         stored TRANSPOSED as [B,H,DH,T] with packed uint2 stores (4 t-rows/store).
// mode 1: linear write + fp32 bias.
__global__ __launch_bounds__(256) void k_gemm_bt(const u16* __restrict__ A, const u16* __restrict__ Bt,
                                                 u16* __restrict__ dst0, u16* __restrict__ dst1,
                                                 const float* __restrict__ bias, float scale, int mode) {
  __shared__ __align__(16) u16 Al[128][40];
  __shared__ __align__(16) u16 Bl[128][40];
  int m0 = blockIdx.y * 128, n0 = blockIdx.x * 128;
  int tid = threadIdx.x;
  int w = tid >> 6, lane = tid & 63, g = lane >> 4, lr = lane & 15;
  int wr = w >> 1, wc = w & 1;
  f32x4 acc[4][4] = {};
  int sr = tid >> 2, sc = tid & 3;
  const u16* Ap0 = &A[(size_t)(m0 + sr) * Dn + sc * 8];
  const u16* Ap1 = &A[(size_t)(m0 + sr + 64) * Dn + sc * 8];
  const u16* Bp0 = &Bt[(size_t)(n0 + sr) * Dn + sc * 8];
  const u16* Bp1 = &Bt[(size_t)(n0 + sr + 64) * Dn + sc * 8];
  int4 ra0 = *(const int4*)Ap0;
  int4 ra1 = *(const int4*)Ap1;
  int4 rb0 = *(const int4*)Bp0;
  int4 rb1 = *(const int4*)Bp1;
  for (int k0 = 0; k0 < Dn; k0 += 32) {
    __syncthreads();
    *(int4*)&Al[sr][sc*8]      = ra0;
    *(int4*)&Al[sr + 64][sc*8] = ra1;
    *(int4*)&Bl[sr][sc*8]      = rb0;
    *(int4*)&Bl[sr + 64][sc*8] = rb1;
    __syncthreads();
    if (k0 + 32 < Dn) {
      ra0 = *(const int4*)(Ap0 + k0 + 32);
      ra1 = *(const int4*)(Ap1 + k0 + 32);
      rb0 = *(const int4*)(Bp0 + k0 + 32);
      rb1 = *(const int4*)(Bp1 + k0 + 32);
    }
    bf16x8 a[4], b[4];
    #pragma unroll
    for (int mi = 0; mi < 4; mi++) a[mi] = *(const bf16x8*)&Al[wr*64 + mi*16 + lr][g*8];
    #pragma unroll
    for (int ni = 0; ni < 4; ni++) b[ni] = *(const bf16x8*)&Bl[wc*64 + ni*16 + lr][g*8];
    #pragma unroll
    for (int mi = 0; mi < 4; mi++)
      #pragma unroll
      for (int ni = 0; ni < 4; ni++)
        acc[mi][ni] = mfma16(a[mi], b[ni], acc[mi][ni]);
  }
  #pragma unroll
  for (int mi = 0; mi < 4; mi++)
    #pragma unroll
    for (int ni = 0; ni < 4; ni++) {
      int row0 = m0 + wr*64 + mi*16 + g*4;
      int col = n0 + wc*64 + ni*16 + lr;
      if (mode == 0) {
        int bb = row0 >> 10, tt0 = row0 & 1023;
        int hh = col >> 6, dd = col & 63;
        if (hh < 16) {
          u16* p = dst0 + (((size_t)(bb*16 + hh) << 10) + (size_t)tt0) * 64 + dd;
          #pragma unroll
          for (int r = 0; r < 4; r++) p[(size_t)r * 64] = f2bf(acc[mi][ni][r] * scale);
        } else {
          // V^T: [b][head][dd][t], 4 consecutive t per lane -> packed 8B store
          union { u16 s[4]; uint2 u; } o;
          #pragma unroll
          for (int r = 0; r < 4; r++) o.s[r] = f2bf(acc[mi][ni][r]);
          *(uint2*)(dst1 + (((size_t)((bb*16 + (hh - 16)) * 64 + dd)) << 10) + tt0) = o.u;
        }
      } else {
        #pragma unroll
        for (int r = 0; r < 4; r++)
          dst0[(size_t)(row0 + r) * Dn + col] = f2bf(acc[mi][ni][r] + bias[col]);
      }
    }
}

// ---------------- flash attention with Music-Transformer skew ----------------
// grid (KVSPLIT*B, H, T/128), block 512 = 8 waves sharing one K/V staging.
// 128 kv per barrier-iter (two 16x64 sub-tiles per wave). Load-issue order is
// arranged for in-order vmcnt retirement: mask+E loads (L2-hot) are issued
// BEFORE the HBM K/V prefetch, so E consumption never queues behind HBM.
// Fixed-max softmax (scores bounded), row-sum via ones-MFMA. REL band carry:
// tile t+1's jt=0 window == tile t's jt=4 -> carried in registers.
__global__ __launch_bounds__(512, 2) void k_attn(const u16* __restrict__ Qb, const u16* __restrict__ Kb,
                                              const u16* __restrict__ VT, const u16* __restrict__ Eb,
                                              const unsigned long long* __restrict__ mbits,
                                              u16* __restrict__ Opart, float* __restrict__ Lpart) {
  __shared__ __align__(16) u16 KlF[128 * 64];   // XOR-swizzled: u16 idx = row*64 + (col ^ ((row&7)<<3))
  __shared__ __align__(16) u16 Vt[64][136];     // V^T tile: Vt[d][kv-local 0..127]
  __shared__ __align__(16) u16 RP[8][16][72];   // per-wave P tile (bf16), reused across sub-tiles
  int h = blockIdx.y;
  int zi = blockIdx.x;            // s*B + b
  int b = zi & 3;
  int kv0 = (zi >> 2) * (Tn / KVSPLIT);
  int kv_end = kv0 + Tn / KVSPLIT;
  int q0 = blockIdx.z * 128;
  int tid = threadIdx.x;
  int w = tid >> 6, lane = tid & 63, g = lane >> 4, lr = lane & 15;
  int qw0 = q0 + w * 16;
  size_t headoff = (size_t)(b * Hn + h) * Tn * DHn;
  bf16x8 qf0 = *(const bf16x8*)&Qb[headoff + (size_t)(qw0 + lr)*64 + g*8];
  bf16x8 qf1 = *(const bf16x8*)&Qb[headoff + (size_t)(qw0 + lr)*64 + 32 + g*8];
  f32x4 O[4] = {};
  f32x4 Os = {0.f, 0.f, 0.f, 0.f};
  union { u16 s[8]; bf16x8 v; } one8;
  #pragma unroll
  for (int j = 0; j < 8; j++) one8.s[j] = 0x3F80u; // bf16 1.0

  // loop-invariant skew-shuffle source lanes + register-set predicates:
  // skew(rowq,col) = REL[rowq][col-rowq+15]; producer lane = same g-group,
  // lane (lr-rowq+15)&15, register-set c (if lr<=rowq) else c+1, same reg r.
  int srcl[4]; bool psel[4];
  #pragma unroll
  for (int r = 0; r < 4; r++) {
    int rowq = g*4 + r;
    srcl[r] = (lane & 48) + ((lr - rowq + 15) & 15);
    psel[r] = (lr <= rowq);
  }
  const unsigned long long* mrow = mbits + ((size_t)(b * Tn + qw0 + g*4) << 4);

  // REL carry prologue: jt=0 window of the first tile
  f32x4 carry = {0.f, 0.f, 0.f, 0.f};
  {
    int rmin0 = kv0 - qw0 + 1008;
    const u16* ep = &Eb[(size_t)(rmin0 + lr) * 64 + g*8];
    carry = mfma16(qf0, *(const bf16x8*)ep, carry);
    carry = mfma16(qf1, *(const bf16x8*)(ep + 32), carry);
  }

  // staging (512 threads, 128-kv iter):
  //   K: 128 rows x 64 cols -> rows tid>>3 and +64, chunk (tid&7)*8 (XOR-swizzled)
  //   V^T: 64 rows x 128 cols -> rows tid>>4 and +32, chunk (tid&15)*8
  int sKr = tid >> 3, sKc = (tid & 7) * 8;
  int kswz = sKc ^ ((sKr & 7) << 3);       // (sKr+64)&7 == sKr&7 -> same swizzle both rows
  int sVr = tid >> 4, sVc = (tid & 15) * 8;
  const u16* Kgs = Kb + headoff + (size_t)sKr * 64 + sKc;
  const u16* Vgs = VT + headoff + (size_t)sVr * 1024 + sVc;
  int4 kA = *(const int4*)(Kgs + (size_t)kv0 * 64);
  int4 kB = *(const int4*)(Kgs + (size_t)(kv0 + 64) * 64);
  int4 vA = *(const int4*)(Vgs + kv0);
  int4 vB = *(const int4*)(Vgs + 32 * 1024 + kv0);

  int kread = (g * 8) ^ ((lr & 7) << 3);      // swizzled col for K fragment, low half
  int kread2 = (32 + g * 8) ^ ((lr & 7) << 3);

  for (int k0 = kv0; k0 < kv_end; k0 += 128) {
    __syncthreads();
    *(int4*)&KlF[sKr * 64 + kswz]        = kA;
    *(int4*)&KlF[(sKr + 64) * 64 + kswz] = kB;
    *(int4*)&Vt[sVr][sVc]                = vA;
    *(int4*)&Vt[sVr + 32][sVc]           = vB;
    __syncthreads();

    // packed mask words for both tiles (L2-hot, issued first)
    uint2 mw[2][4];
    #pragma unroll
    for (int t = 0; t < 2; t++)
      #pragma unroll
      for (int r = 0; r < 4; r++)
        mw[t][r] = *(const uint2*)(mrow + (size_t)r * 16 + (k0 >> 6) + t);

    int rmin0 = k0 - qw0 + 1008;
    bf16x8 pa00, pa01, pa10, pa11;

    // ================= sub-tile 0 =================
    f32x4 Rm0[5];
    Rm0[0] = carry;
    __builtin_amdgcn_s_setprio(1);
    #pragma unroll
    for (int jt = 1; jt < 5; jt++) {
      const u16* ep = &Eb[(size_t)(rmin0 + jt*16 + lr) * 64 + g*8];
      f32x4 R = {0.f, 0.f, 0.f, 0.f};
      R = mfma16(qf0, *(const bf16x8*)ep, R);
      R = mfma16(qf1, *(const bf16x8*)(ep + 32), R);
      Rm0[jt] = R;
    }
    f32x4 S0[4];
    #pragma unroll
    for (int c = 0; c < 4; c++) {
      int krow = c*16 + lr;
      f32x4 z = {0.f, 0.f, 0.f, 0.f};
      z = mfma16(qf0, *(const bf16x8*)&KlF[krow*64 + kread], z);
      z = mfma16(qf1, *(const bf16x8*)&KlF[krow*64 + kread2], z);
      S0[c] = z;
    }
    __builtin_amdgcn_s_setprio(0);
    {
      float sh[5][4];
      #pragma unroll
      for (int s5 = 0; s5 < 5; s5++)
        #pragma unroll
        for (int r = 0; r < 4; r++)
          sh[s5][r] = __shfl(Rm0[s5][r], srcl[r], 64);
      #pragma unroll
      for (int c = 0; c < 4; c++)
        #pragma unroll
        for (int r = 0; r < 4; r++) {
          float s = S0[c][r] + (psel[r] ? sh[c][r] : sh[c+1][r]);
          unsigned bit;
          if (c == 0)      bit = (mw[0][r].x >> lr) & 1u;
          else if (c == 1) bit = (mw[0][r].x >> (16 + lr)) & 1u;
          else if (c == 2) bit = (mw[0][r].y >> lr) & 1u;
          else             bit = (mw[0][r].y >> (16 + lr)) & 1u;
          s = bit ? -1e9f : s;
          RP[w][g*4 + r][c*16 + lr] = f2bf(__builtin_amdgcn_exp2f(s));
        }
      pa00 = *(const bf16x8*)&RP[w][lr][g*8];
      pa01 = *(const bf16x8*)&RP[w][lr][32 + g*8];
    }

    // ================= sub-tile 1: REL E-loads first =================
    f32x4 Rm1[5];
    Rm1[0] = Rm0[4];
    __builtin_amdgcn_s_setprio(1);
    #pragma unroll
    for (int jt = 1; jt < 5; jt++) {
      const u16* ep = &Eb[(size_t)(rmin0 + 64 + jt*16 + lr) * 64 + g*8];
      f32x4 R = {0.f, 0.f, 0.f, 0.f};
      R = mfma16(qf0, *(const bf16x8*)ep, R);
      R = mfma16(qf1, *(const bf16x8*)(ep + 32), R);
      Rm1[jt] = R;
    }
    __builtin_amdgcn_s_setprio(0);
    carry = Rm1[4];

    // HBM K/V prefetch for next iter: issued AFTER all L2 loads of this iter
    // (in-order vmcnt retirement -> must be youngest). sched_barrier pins it.
    __builtin_amdgcn_sched_barrier(0);
    if (k0 + 128 < kv_end) {
      kA = *(const int4*)(Kgs + (size_t)(k0 + 128) * 64);
      kB = *(const int4*)(Kgs + (size_t)(k0 + 192) * 64);
      vA = *(const int4*)(Vgs + k0 + 128);
      vB = *(const int4*)(Vgs + 32 * 1024 + k0 + 128);
    }
    __builtin_amdgcn_sched_barrier(0);

    // sub-tile 1: S + softmax
    f32x4 S1[4];
    __builtin_amdgcn_s_setprio(1);
    #pragma unroll
    for (int c = 0; c < 4; c++) {
      int krow = 64 + c*16 + lr;
      f32x4 z = {0.f, 0.f, 0.f, 0.f};
      z = mfma16(qf0, *(const bf16x8*)&KlF[krow*64 + kread], z);
      z = mfma16(qf1, *(const bf16x8*)&KlF[krow*64 + kread2], z);
      S1[c] = z;
    }
    __builtin_amdgcn_s_setprio(0);
    {
      float sh[5][4];
      #pragma unroll
      for (int s5 = 0; s5 < 5; s5++)
        #pragma unroll
        for (int r = 0; r < 4; r++)
          sh[s5][r] = __shfl(Rm1[s5][r], srcl[r], 64);
      #pragma unroll
      for (int c = 0; c < 4; c++)
        #pragma unroll
        for (int r = 0; r < 4; r++) {
          float s = S1[c][r] + (psel[r] ? sh[c][r] : sh[c+1][r]);
          unsigned bit;
          if (c == 0)      bit = (mw[1][r].x >> lr) & 1u;
          else if (c == 1) bit = (mw[1][r].x >> (16 + lr)) & 1u;
          else if (c == 2) bit = (mw[1][r].y >> lr) & 1u;
          else             bit = (mw[1][r].y >> (16 + lr)) & 1u;
          s = bit ? -1e9f : s;
          RP[w][g*4 + r][c*16 + lr] = f2bf(__builtin_amdgcn_exp2f(s));
        }
      pa10 = *(const bf16x8*)&RP[w][lr][g*8];
      pa11 = *(const bf16x8*)&RP[w][lr][32 + g*8];
    }

    // ================= PV + row-sum (LDS + MFMA only) =================
    __builtin_amdgcn_s_setprio(1);
    #pragma unroll
    for (int ct = 0; ct < 4; ct++) {
      bf16x8 vf0 = *(const bf16x8*)&Vt[ct*16 + lr][g*8];
      bf16x8 vf1 = *(const bf16x8*)&Vt[ct*16 + lr][32 + g*8];
      O[ct] = mfma16(pa00, vf0, O[ct]);
      O[ct] = mfma16(pa01, vf1, O[ct]);
      bf16x8 vf2 = *(const bf16x8*)&Vt[ct*16 + lr][64 + g*8];
      bf16x8 vf3 = *(const bf16x8*)&Vt[ct*16 + lr][96 + g*8];
      O[ct] = mfma16(pa10, vf2, O[ct]);
      O[ct] = mfma16(pa11, vf3, O[ct]);
    }
    Os = mfma16(pa00, one8.v, Os);
    Os = mfma16(pa01, one8.v, Os);
    Os = mfma16(pa10, one8.v, Os);
    Os = mfma16(pa11, one8.v, Os);
    __builtin_amdgcn_s_setprio(0);
  }
  // store unnormalized partial O (bf16) and row-sums l (f32)
  #pragma unroll
  for (int ct = 0; ct < 4; ct++)
    #pragma unroll
    for (int r = 0; r < 4; r++) {
      int rowq = g*4 + r, col = ct*16 + lr;
      Opart[((size_t)zi * Tn + qw0 + rowq) * 1024 + h*64 + col] = f2bf(O[ct][r]);
    }
  if (lr == 0) {
    #pragma unroll
    for (int r = 0; r < 4; r++)
      Lpart[((size_t)zi * Hn + h) * Tn + qw0 + g*4 + r] = Os[r];
  }
}

// ---------------- combine KV-split partials: ctx = (sum O_s) / (sum l_s) ----------------
__global__ __launch_bounds__(256) void k_combine(const u16* __restrict__ Op, const float* __restrict__ Lp,
                                                 u16* __restrict__ ctx) {
  int m = blockIdx.x;            // b*T + t
  int b = m >> 10, t = m & 1023;
  int tid = threadIdx.x;
  int j0 = tid * 4, h = j0 >> 6;
  float l = Lp[((size_t)b * Hn + h) * Tn + t] +
            Lp[((size_t)(4 + b) * Hn + h) * Tn + t];
  float invl = 1.f / l;
  union { uint2 u; u16 s[4]; } a, c;
  a.u = *(const uint2*)&Op[((size_t)b * Tn + t) * 1024 + j0];
  c.u = *(const uint2*)&Op[((size_t)(4 + b) * Tn + t) * 1024 + j0];
  union { u16 s[4]; uint2 u; } o;
  #pragma unroll
  for (int i = 0; i < 4; i++)
    o.s[i] = f2bf((bf2f(a.s[i]) + bf2f(c.s[i])) * invl);
  *(uint2*)&ctx[((size_t)b * Tn + t) * 1024 + j0] = o.u;
}

// ---------------- residual + LayerNorm ----------------
__global__ __launch_bounds__(256) void k_ln(const float* __restrict__ x, const u16* __restrict__ o,
                                            const float* __restrict__ gamma, const float* __restrict__ beta,
                                            float* __restrict__ out) {
  int m = blockIdx.x, tid = threadIdx.x;
  int w = tid >> 6, lane = tid & 63;
  const float* xr = x + (size_t)m * Dn;
  const u16* orow = o + (size_t)m * Dn;
  float4 xv = *(const float4*)&xr[tid*4];
  union { uint2 u; u16 s[4]; } ou;
  ou.u = *(const uint2*)&orow[tid*4];
  float y[4];
  y[0] = xv.x + bf2f(ou.s[0]);
  y[1] = xv.y + bf2f(ou.s[1]);
  y[2] = xv.z + bf2f(ou.s[2]);
  y[3] = xv.w + bf2f(ou.s[3]);
  float s = y[0]+y[1]+y[2]+y[3];
  float s2 = y[0]*y[0]+y[1]*y[1]+y[2]*y[2]+y[3]*y[3];
  #pragma unroll
  for (int off = 1; off < 64; off <<= 1) { s += __shfl_xor(s, off); s2 += __shfl_xor(s2, off); }
  __shared__ float red[8];
  if (lane == 0) { red[w] = s; red[4 + w] = s2; }
  __syncthreads();
  float Sa = red[0]+red[1]+red[2]+red[3];
  float Sb = red[4]+red[5]+red[6]+red[7];
  float mu = Sa * (1.f/1024.f);
  float var = Sb * (1.f/1024.f) - mu*mu;
  float rstd = rsqrtf(var + 1e-5f);
  #pragma unroll
  for (int i = 0; i < 4; i++) {
    int j = tid*4 + i;
    out[(size_t)m*Dn + j] = (y[i] - mu) * rstd * gamma[j] + beta[j];
  }
}

extern "C" void kernel_launch(void* const* d_in, const int* in_sizes, int n_in,
                              void* d_out, int out_size, void* d_ws, size_t ws_size,
                              hipStream_t stream) {
  const float* x    = (const float*)d_in[0];
  const float* ctxI = (const float*)d_in[1];
  const unsigned char* mask = (const unsigned char*)d_in[2];
  const float* lut  = (const float*)d_in[3];
  const float* Wq   = (const float*)d_in[4];
  const float* Wk   = (const float*)d_in[5];
  const float* Wv   = (const float*)d_in[6];
  const float* Wo   = (const float*)d_in[7];
  const float* bo   = (const float*)d_in[8];
  const float* gamma= (const float*)d_in[9];
  const float* beta = (const float*)d_in[10];
  float* out = (float*)d_out;

  u16* xbf = (u16*)d_ws;
  u16* cbf  = xbf + 4194304;
  u16* WqT  = cbf + 4194304;
  u16* WkT  = WqT + 1048576;
  u16* WvT  = WkT + 1048576;   // contiguous with WkT -> fused KV GEMM reads [2048][1024]
  u16* WoT  = WvT + 1048576;
  u16* Ebf  = WoT + 1048576;
  u16* Qbf  = Ebf + 131072;
  u16* Kbf  = Qbf + 4194304;
  u16* Vbf  = Kbf + 4194304;   // holds V^T [B,H,DH,T]
  u16* ctxb = Vbf + 4194304;
  u16* obf  = ctxb + 4194304;
  unsigned long long* mbits = (unsigned long long*)(obf + 4194304); // 65536 words = 512 KB

  // KV-split partial buffers alias DEAD regions during attn:
  //   Opart (16.8 MB, bf16, [2*B][T][H*DH]) over xbf+cbf (consumed by the Q/KV GEMMs).
  //   Lpart (512 KB, f32, [2*B][H][T]) over obf (first written by the O-GEMM, later).
  u16* Opart = xbf;
  float* Lpart = (float*)obf;

  k_maskpack<<<16384, 256, 0, stream>>>(mask, mbits);
  k_convert<<<4096, 256, 0, stream>>>(x, xbf, 4194304);
  k_convert<<<4096, 256, 0, stream>>>(ctxI, cbf, 4194304);
  k_convert<<<128, 256, 0, stream>>>(lut, Ebf, 131008);
  dim3 tb(32, 8), tg(32, 32);
  k_transpose_convert<<<tg, tb, 0, stream>>>(Wq, WqT);
  k_transpose_convert<<<tg, tb, 0, stream>>>(Wk, WkT);
  k_transpose_convert<<<tg, tb, 0, stream>>>(Wv, WvT);
  k_transpose_convert<<<tg, tb, 0, stream>>>(Wo, WoT);
  k_gemm_bt<<<dim3(8, 32),  256, 0, stream>>>(xbf, WqT, Qbf, nullptr, nullptr, QSCALE, 0);
  k_gemm_bt<<<dim3(16, 32), 256, 0, stream>>>(cbf, WkT, Kbf, Vbf,    nullptr, 1.0f,   0);
  k_attn<<<dim3(8, 16, 8), 512, 0, stream>>>(Qbf, Kbf, Vbf, Ebf, mbits, Opart, Lpart);
  k_combine<<<4096, 256, 0, stream>>>(Opart, Lpart, ctxb);
  k_gemm_bt<<<dim3(8, 32),  256, 0, stream>>>(ctxb, WoT, obf, nullptr, bo, 1.0f, 1);
  k_ln<<<4096, 256, 0, stream>>>(x, obf, gamma, beta, out);
}